// Round 9
// baseline (287.949 us; speedup 1.0000x reference)
//
#include <hip/hip_runtime.h>
#include <math.h>

#define TILE 4096          // edges per partition tile
#define CSHIFT 11          // coarse bucket = dst >> 11  (2048 nodes)
#define CMASK 2047
#define NCMAX 64

// ---------- helpers ----------

__device__ __forceinline__ unsigned int pack_bf16(float a, float b) {
  unsigned int ua = __float_as_uint(a);
  ua += 0x7FFFu + ((ua >> 16) & 1u);
  unsigned int ub = __float_as_uint(b);
  ub += 0x7FFFu + ((ub >> 16) & 1u);
  return (ua >> 16) | (ub & 0xFFFF0000u);
}

// acc[0..7] += bf16x8(hv)
__device__ __forceinline__ void add8(float* acc, uint4 hv) {
  unsigned int u[4] = {hv.x, hv.y, hv.z, hv.w};
#pragma unroll
  for (int i = 0; i < 4; ++i) {
    acc[2 * i]     += __uint_as_float(u[i] << 16);
    acc[2 * i + 1] += __uint_as_float(u[i] & 0xFFFF0000u);
  }
}

__device__ __forceinline__ void fma4(float4& acc, float s, const float4& w) {
  acc.x = fmaf(s, w.x, acc.x);
  acc.y = fmaf(s, w.y, acc.y);
  acc.z = fmaf(s, w.z, acc.z);
  acc.w = fmaf(s, w.w, acc.w);
}

// ---------- CSR build: two-level LDS-staged split ----------

__global__ void zero_kernel(int* __restrict__ p, int n) {
  int i = blockIdx.x * blockDim.x + threadIdx.x;
  if (i < n) p[i] = 0;
}

__global__ __launch_bounds__(256) void coarse_hist_kernel(const int* __restrict__ dst,
    int* __restrict__ ccnt, int e) {
  __shared__ int h[NCMAX];
  if (threadIdx.x < NCMAX) h[threadIdx.x] = 0;
  __syncthreads();
  for (int i = blockIdx.x * 256 + threadIdx.x; i < e; i += gridDim.x * 256)
    atomicAdd(&h[dst[i] >> CSHIFT], 1);
  __syncthreads();
  if (threadIdx.x < NCMAX && h[threadIdx.x])
    atomicAdd(&ccnt[threadIdx.x * 16], h[threadIdx.x]);
}

// single wave: exclusive scan of nc coarse counts; init cursors; off[n]=e
__global__ __launch_bounds__(64) void coarse_scan_kernel(const int* __restrict__ ccnt,
    int* __restrict__ coff, int* __restrict__ ccur, int* __restrict__ off,
    int nc, int n, int e) {
  int t = threadIdx.x;
  int v = (t < nc) ? ccnt[t * 16] : 0;
  int incl = v;
#pragma unroll
  for (int ofs = 1; ofs < 64; ofs <<= 1) {
    int w = __shfl_up(incl, ofs);
    if (t >= ofs) incl += w;
  }
  int excl = incl - v;
  if (t < nc) { coff[t] = excl; ccur[t * 16] = excl; }
  if (t == nc - 1) coff[nc] = incl;
  if (t == 0) off[n] = e;
}

// LDS-staged partition: sort a 4096-edge tile by coarse bucket in LDS, reserve
// a global range per bucket with ONE atomic, stream out contiguous segments.
__global__ __launch_bounds__(256) void coarse_partition_kernel(const int* __restrict__ src,
    const int* __restrict__ dst, int* __restrict__ ccur,
    unsigned int* __restrict__ packed, int e) {
  __shared__ unsigned int stage[TILE];
  __shared__ unsigned char bid[TILE];
  __shared__ int hist[NCMAX], excl[NCMAX], gbase[NCMAX], lcur[NCMAX];
  int ntiles = (e + TILE - 1) / TILE;
  for (int tile = blockIdx.x; tile < ntiles; tile += gridDim.x) {
    int i0 = tile * TILE;
    int cnt = e - i0; if (cnt > TILE) cnt = TILE;
    if (threadIdx.x < NCMAX) hist[threadIdx.x] = 0;
    __syncthreads();
    int myS[16], myD[16];
#pragma unroll
    for (int k = 0; k < 16; ++k) {
      int li = threadIdx.x + k * 256;
      if (li < cnt) {
        myS[k] = src[i0 + li];
        myD[k] = dst[i0 + li];
        atomicAdd(&hist[myD[k] >> CSHIFT], 1);
      }
    }
    __syncthreads();
    if (threadIdx.x < NCMAX) {  // wave 0: scan 64 buckets
      int t = threadIdx.x;
      int v = hist[t];
      int incl = v;
#pragma unroll
      for (int ofs = 1; ofs < 64; ofs <<= 1) {
        int w = __shfl_up(incl, ofs);
        if (t >= ofs) incl += w;
      }
      excl[t] = incl - v;
      lcur[t] = incl - v;
    }
    __syncthreads();
#pragma unroll
    for (int k = 0; k < 16; ++k) {
      int li = threadIdx.x + k * 256;
      if (li < cnt) {
        int c = myD[k] >> CSHIFT;
        int p = atomicAdd(&lcur[c], 1);
        stage[p] = (unsigned int)myS[k] | ((unsigned int)(myD[k] & CMASK) << 17);
        bid[p] = (unsigned char)c;
      }
    }
    __syncthreads();
    if (threadIdx.x < NCMAX) {
      int t = threadIdx.x;
      int cc = lcur[t] - excl[t];
      gbase[t] = cc ? atomicAdd(&ccur[t * 16], cc) : 0;
    }
    __syncthreads();
    for (int i = threadIdx.x; i < cnt; i += 256) {
      int c = bid[i];
      packed[gbase[c] + (i - excl[c])] = stage[i];
    }
    __syncthreads();  // protect hist/stage reuse
  }
}

// one block per coarse bucket: counting sort 2048 node sub-buckets -> csr, off, dinv.
__global__ __launch_bounds__(512) void csr_fine_kernel(const unsigned int* __restrict__ packed,
    const int* __restrict__ coff, int* __restrict__ off, float* __restrict__ dinv,
    int* __restrict__ csr, int n) {
  __shared__ int lh[2048];
  __shared__ int lsum[512];
  int b = blockIdx.x;
  int t = threadIdx.x;
  int e0 = coff[b], e1 = coff[b + 1];
  int node0 = b << CSHIFT;
  for (int i = t; i < 2048; i += 512) lh[i] = 0;
  __syncthreads();
  for (int i = e0 + t; i < e1; i += 512) atomicAdd(&lh[packed[i] >> 17], 1);
  __syncthreads();
  int base = t * 4;
  int v0 = lh[base], v1 = lh[base + 1], v2 = lh[base + 2], v3 = lh[base + 3];
  int tsum = v0 + v1 + v2 + v3;
  lsum[t] = tsum;
  __syncthreads();
  for (int ofs = 1; ofs < 512; ofs <<= 1) {
    int add = (t >= ofs) ? lsum[t - ofs] : 0;
    __syncthreads();
    lsum[t] += add;
    __syncthreads();
  }
  int ex = lsum[t] - tsum;
  int exc0 = ex, exc1 = ex + v0, exc2 = ex + v0 + v1, exc3 = ex + v0 + v1 + v2;
  lh[base] = exc0; lh[base + 1] = exc1; lh[base + 2] = exc2; lh[base + 3] = exc3;
  int node = node0 + base;
  if (node < n)     { off[node]     = e0 + exc0; dinv[node]     = rsqrtf((float)(v0 + 1)); }
  if (node + 1 < n) { off[node + 1] = e0 + exc1; dinv[node + 1] = rsqrtf((float)(v1 + 1)); }
  if (node + 2 < n) { off[node + 2] = e0 + exc2; dinv[node + 2] = rsqrtf((float)(v2 + 1)); }
  if (node + 3 < n) { off[node + 3] = e0 + exc3; dinv[node + 3] = rsqrtf((float)(v3 + 1)); }
  __syncthreads();
  for (int i = e0 + t; i < e1; i += 512) {
    unsigned int p = packed[i];
    int nl = p >> 17;
    int pos = atomicAdd(&lh[nl], 1);
    csr[e0 + pos] = (int)(p & 0x1FFFFu);
  }
}

// ---------- h1' = dinv * (x @ W1), output bf16 ----------
// W (32KB f32) in LDS, loaded ONCE (single barrier). Each wave owns 8 rows;
// lane = output column. Per k-quad: 4 conflict-free ds_read_b32 of W +
// 8 uniform-address float4 broadcasts of x + 32 FMA on 8 independent chains.
// No barriers in the loop; ~40 VGPR -> high occupancy.
__global__ __launch_bounds__(256) void gemm1_kernel(const float* __restrict__ x,
    const float* __restrict__ W1, const float* __restrict__ dinv,
    unsigned int* __restrict__ h1, int n) {
  __shared__ float Ws[128 * 64];  // 32 KB
  for (int i = threadIdx.x; i < 128 * 16; i += 256)
    ((float4*)Ws)[i] = ((const float4*)W1)[i];
  __syncthreads();
  int lane = threadIdx.x & 63;
  int gw = blockIdx.x * 4 + (threadIdx.x >> 6);
  int ngw = gridDim.x * 4;
  int ngroups = (n + 7) >> 3;
  for (int g = gw; g < ngroups; g += ngw) {
    int row0 = g * 8;
    const float* xr = x + (size_t)row0 * 128;
    float acc[8];
#pragma unroll
    for (int r = 0; r < 8; ++r) acc[r] = 0.f;
#pragma unroll 4
    for (int kq = 0; kq < 32; ++kq) {
      float w0 = Ws[(4 * kq + 0) * 64 + lane];
      float w1 = Ws[(4 * kq + 1) * 64 + lane];
      float w2 = Ws[(4 * kq + 2) * 64 + lane];
      float w3 = Ws[(4 * kq + 3) * 64 + lane];
#pragma unroll
      for (int r = 0; r < 8; ++r) {
        float4 xv = *(const float4*)(xr + (size_t)r * 128 + kq * 4);  // broadcast
        acc[r] = fmaf(xv.w, w3, fmaf(xv.z, w2, fmaf(xv.y, w1, fmaf(xv.x, w0, acc[r]))));
      }
    }
#pragma unroll
    for (int r = 0; r < 8; ++r) {
      int row = row0 + r;
      if (row < n) {
        float val = dinv[row] * acc[r];
        float pv = __shfl_xor(val, 1);
        if (!(lane & 1)) {
          h1[(size_t)row * 32 + (lane >> 1)] = pack_bf16(val, pv);
        }
      }
    }
  }
}

// ---------- aggregation ----------
// 16 edge-slots x 4 feature-lanes per wave. h rows dinv-prefolded (h'=dinv*h).
// acc = h'[node] + sum_{e:dst=node} h'[src];  result = dinv[node]*acc.
// Recursive-halving shfl reduce leaves ONE feature per lane (static reg indices).
// EPI=1: out = bf16( dinv * tanh(result + bias) ); EPI=0: out = bf16(result).
template <int EPI>
__global__ __launch_bounds__(256) void agg_kernel(const uint4* __restrict__ h4,
    const int* __restrict__ off, const int* __restrict__ csr,
    const float* __restrict__ dinv, const float* __restrict__ bias,
    unsigned int* __restrict__ out, int n) {
  int node = blockIdx.x * 4 + (threadIdx.x >> 6);
  if (node >= n) return;
  int lane = threadIdx.x & 63;
  int j = lane >> 2;   // edge slot 0..15
  int l = lane & 3;    // feature quarter (16 bf16 = 32B = 2 uint4)
  float acc[16];
#pragma unroll
  for (int i = 0; i < 16; ++i) acc[i] = 0.f;
  if (j == 0) {  // self loop
    uint4 a = h4[(size_t)node * 8 + l * 2];
    uint4 b = h4[(size_t)node * 8 + l * 2 + 1];
    add8(acc, a);
    add8(acc + 8, b);
  }
  int e1 = off[node + 1];
  for (int ee = off[node] + j; ee < e1; ee += 16) {
    int s = __builtin_nontemporal_load(&csr[ee]);
    uint4 a = h4[(size_t)s * 8 + l * 2];
    uint4 b = h4[(size_t)s * 8 + l * 2 + 1];
    add8(acc, a);
    add8(acc + 8, b);
  }
  // recursive-halving reduce over the 16 slots; feature count 16 -> 1
#pragma unroll
  for (int i = 0; i < 8; ++i) {
    float tlo = acc[i]     + __shfl_xor(acc[i], 4);
    float thi = acc[i + 8] + __shfl_xor(acc[i + 8], 4);
    acc[i] = (j & 1) ? thi : tlo;
  }
#pragma unroll
  for (int i = 0; i < 4; ++i) {
    float tlo = acc[i]     + __shfl_xor(acc[i], 8);
    float thi = acc[i + 4] + __shfl_xor(acc[i + 4], 8);
    acc[i] = (j & 2) ? thi : tlo;
  }
#pragma unroll
  for (int i = 0; i < 2; ++i) {
    float tlo = acc[i]     + __shfl_xor(acc[i], 16);
    float thi = acc[i + 2] + __shfl_xor(acc[i + 2], 16);
    acc[i] = (j & 4) ? thi : tlo;
  }
  float a0, a1;
  a0 = acc[0] + __shfl_xor(acc[0], 32);
  a1 = acc[1] + __shfl_xor(acc[1], 32);
  float a = (j & 8) ? a1 : a0;
  // this lane now owns feature f = l*16 + j0*8 + j1*4 + j2*2 + j3
  int f = l * 16 + ((j & 1) << 3) + ((j & 2) << 1) + ((j >> 2) & 1) * 2 + ((j >> 3) & 1);
  float di = dinv[node];
  float val;
  if (EPI) {
    val = di * tanhf(fmaf(di, a, bias[f]));
  } else {
    val = di * a;
  }
  // pack feature pairs (f even with f+1, partner lane = lane^32) and store
  float pv = __shfl_xor(val, 32);
  if (!(j & 8)) {  // f even
    unsigned int w = pack_bf16(val, pv);
    int half = l * 8 + ((j & 1) << 2) + (j & 2) + ((j >> 2) & 1);  // f/2
    out[(size_t)node * 32 + half] = w;
  }
}

// ---------- final: mean/logvar GEMMs + reparam ----------
__global__ __launch_bounds__(256) void final_kernel(const unsigned int* __restrict__ aggb,
    const float* __restrict__ Wm, const float* __restrict__ bm,
    const float* __restrict__ Wv, const float* __restrict__ bv,
    const float* __restrict__ noise, float* __restrict__ outZ,
    float* __restrict__ outM, float* __restrict__ outLv, int n) {
  __shared__ float WmS[64 * 32];
  __shared__ float WvS[64 * 32];
  __shared__ float aggS[64 * 68];  // stride 68 breaks bank conflicts
  for (int i = threadIdx.x; i < 64 * 8; i += 256) {
    ((float4*)WmS)[i] = ((const float4*)Wm)[i];
    ((float4*)WvS)[i] = ((const float4*)Wv)[i];
  }
  int row0 = blockIdx.x * 64;
  int nrow = n - row0; if (nrow > 64) nrow = 64;
  for (int i = threadIdx.x; i < 64 * 16; i += 256) {
    int r = i >> 4, g = i & 15;
    uint2 u = make_uint2(0u, 0u);
    if (r < nrow) u = ((const uint2*)aggb)[(size_t)(row0 + r) * 16 + g];
    float* d = &aggS[r * 68 + g * 4];
    d[0] = __uint_as_float(u.x << 16);
    d[1] = __uint_as_float(u.x & 0xFFFF0000u);
    d[2] = __uint_as_float(u.y << 16);
    d[3] = __uint_as_float(u.y & 0xFFFF0000u);
  }
  __syncthreads();
  int c4 = (threadIdx.x & 7) * 4;
  int r2 = (threadIdx.x >> 3) * 2;
  float4 am[2], av[2];
#pragma unroll
  for (int i = 0; i < 2; ++i) {
    am[i] = make_float4(0.f, 0.f, 0.f, 0.f);
    av[i] = make_float4(0.f, 0.f, 0.f, 0.f);
  }
#pragma unroll 4
  for (int kq = 0; kq < 16; ++kq) {
    float4 xa[2], wm[4], wv[4];
#pragma unroll
    for (int i = 0; i < 2; ++i) xa[i] = *(const float4*)&aggS[(r2 + i) * 68 + kq * 4];
#pragma unroll
    for (int q = 0; q < 4; ++q) {
      wm[q] = *(const float4*)&WmS[(kq * 4 + q) * 32 + c4];
      wv[q] = *(const float4*)&WvS[(kq * 4 + q) * 32 + c4];
    }
#pragma unroll
    for (int i = 0; i < 2; ++i) {
      fma4(am[i], xa[i].x, wm[0]); fma4(am[i], xa[i].y, wm[1]);
      fma4(am[i], xa[i].z, wm[2]); fma4(am[i], xa[i].w, wm[3]);
      fma4(av[i], xa[i].x, wv[0]); fma4(av[i], xa[i].y, wv[1]);
      fma4(av[i], xa[i].z, wv[2]); fma4(av[i], xa[i].w, wv[3]);
    }
  }
  float4 bmv = *(const float4*)&bm[c4];
  float4 bvv = *(const float4*)&bv[c4];
#pragma unroll
  for (int i = 0; i < 2; ++i) {
    int row = row0 + r2 + i;
    if (row < n) {
      float4 m = am[i]; m.x += bmv.x; m.y += bmv.y; m.z += bmv.z; m.w += bmv.w;
      float4 v = av[i]; v.x += bvv.x; v.y += bvv.y; v.z += bvv.z; v.w += bvv.w;
      size_t oi = (size_t)row * 8 + (threadIdx.x & 7);
      float4 nz = ((const float4*)noise)[oi];
      float4 z;
      z.x = fmaf(nz.x, expf(0.5f * v.x), m.x);
      z.y = fmaf(nz.y, expf(0.5f * v.y), m.y);
      z.z = fmaf(nz.z, expf(0.5f * v.z), m.z);
      z.w = fmaf(nz.w, expf(0.5f * v.w), m.w);
      ((float4*)outZ)[oi] = z;
      ((float4*)outM)[oi] = m;
      ((float4*)outLv)[oi] = v;
    }
  }
}

// ---------- launch ----------

extern "C" void kernel_launch(void* const* d_in, const int* in_sizes, int n_in,
                              void* d_out, int out_size, void* d_ws, size_t ws_size,
                              hipStream_t stream) {
  const float* x     = (const float*)d_in[0];
  const int*   edge  = (const int*)d_in[1];
  const float* W1    = (const float*)d_in[2];
  const float* b1    = (const float*)d_in[3];
  const float* Wm    = (const float*)d_in[4];
  const float* bm    = (const float*)d_in[5];
  const float* Wv    = (const float*)d_in[6];
  const float* bv    = (const float*)d_in[7];
  const float* noise = (const float*)d_in[8];
  int n = in_sizes[0] / 128;
  int e = in_sizes[1] / 2;
  const int* src = edge;
  const int* dst = edge + e;
  int nc = (n + CMASK) >> CSHIFT;   // 49 coarse buckets of 2048 nodes

  // workspace layout (int units, 16B-aligned segments)
  int* ccnt = (int*)d_ws;                          // NCMAX*16 (1 per 64B line)
  int* ccur = ccnt + NCMAX * 16;                   // NCMAX*16
  int* coff = ccur + NCMAX * 16;                   // NCMAX+1 (+pad)
  int* off  = coff + (NCMAX + 4);                  // n+1 (+pad)
  float* dinv = (float*)(off + ((n + 4) & ~3));    // n
  unsigned int* packed = (unsigned int*)(dinv + ((n + 3) & ~3)); // e
  int* csr  = (int*)(packed + ((e + 3) & ~3));     // e
  unsigned int* h1b = (unsigned int*)(csr + ((e + 3) & ~3)); // n*32 (bf16 h1')
  unsigned int* hb  = h1b + (size_t)n * 32;                  // n*32 (bf16 h')
  unsigned int* aggb = hb + (size_t)n * 32;                  // n*32 (bf16 agg2)

  float* outZ  = (float*)d_out;
  float* outM  = outZ + (size_t)n * 32;
  float* outLv = outM + (size_t)n * 32;

  int ntiles = (e + TILE - 1) / TILE;

  zero_kernel<<<(NCMAX * 16 + 255) / 256, 256, 0, stream>>>(ccnt, NCMAX * 16);
  coarse_hist_kernel<<<256, 256, 0, stream>>>(dst, ccnt, e);
  coarse_scan_kernel<<<1, 64, 0, stream>>>(ccnt, coff, ccur, off, nc, n, e);
  coarse_partition_kernel<<<ntiles, 256, 0, stream>>>(src, dst, ccur, packed, e);
  csr_fine_kernel<<<nc, 512, 0, stream>>>(packed, coff, off, dinv, csr, n);
  gemm1_kernel<<<1280, 256, 0, stream>>>(x, W1, dinv, h1b, n);
  agg_kernel<1><<<(n + 3) / 4, 256, 0, stream>>>((const uint4*)h1b, off, csr, dinv, b1, hb, n);
  agg_kernel<0><<<(n + 3) / 4, 256, 0, stream>>>((const uint4*)hb, off, csr, dinv, b1, aggb, n);
  final_kernel<<<(n + 63) / 64, 256, 0, stream>>>(aggb, Wm, bm, Wv, bv, noise, outZ, outM, outLv, n);
}

// Round 10
// 195.576 us; speedup vs baseline: 1.4723x; 1.4723x over previous
//
#include <hip/hip_runtime.h>
#include <math.h>

#define TILE 4096          // edges per partition tile
#define CSHIFT 11          // coarse bucket = dst >> 11  (2048 nodes)
#define CMASK 2047
#define NCMAX 64

typedef __attribute__((ext_vector_type(8))) short bf16x8;   // 8 bf16 (4 VGPRs)
typedef __attribute__((ext_vector_type(4))) float f32x4;

// ---------- helpers ----------

__device__ __forceinline__ unsigned int pack_bf16(float a, float b) {
  unsigned int ua = __float_as_uint(a);
  ua += 0x7FFFu + ((ua >> 16) & 1u);
  unsigned int ub = __float_as_uint(b);
  ub += 0x7FFFu + ((ub >> 16) & 1u);
  return (ua >> 16) | (ub & 0xFFFF0000u);
}

// acc[0..7] += bf16x8(hv)
__device__ __forceinline__ void add8(float* acc, uint4 hv) {
  unsigned int u[4] = {hv.x, hv.y, hv.z, hv.w};
#pragma unroll
  for (int i = 0; i < 4; ++i) {
    acc[2 * i]     += __uint_as_float(u[i] << 16);
    acc[2 * i + 1] += __uint_as_float(u[i] & 0xFFFF0000u);
  }
}

__device__ __forceinline__ void fma4(float4& acc, float s, const float4& w) {
  acc.x = fmaf(s, w.x, acc.x);
  acc.y = fmaf(s, w.y, acc.y);
  acc.z = fmaf(s, w.z, acc.z);
  acc.w = fmaf(s, w.w, acc.w);
}

// ---------- CSR build: two-level LDS-staged split ----------

__global__ void zero_kernel(int* __restrict__ p, int n) {
  int i = blockIdx.x * blockDim.x + threadIdx.x;
  if (i < n) p[i] = 0;
}

__global__ __launch_bounds__(256) void coarse_hist_kernel(const int* __restrict__ dst,
    int* __restrict__ ccnt, int e) {
  __shared__ int h[NCMAX];
  if (threadIdx.x < NCMAX) h[threadIdx.x] = 0;
  __syncthreads();
  for (int i = blockIdx.x * 256 + threadIdx.x; i < e; i += gridDim.x * 256)
    atomicAdd(&h[dst[i] >> CSHIFT], 1);
  __syncthreads();
  if (threadIdx.x < NCMAX && h[threadIdx.x])
    atomicAdd(&ccnt[threadIdx.x * 16], h[threadIdx.x]);
}

// single wave: exclusive scan of nc coarse counts; init cursors; off[n]=e
__global__ __launch_bounds__(64) void coarse_scan_kernel(const int* __restrict__ ccnt,
    int* __restrict__ coff, int* __restrict__ ccur, int* __restrict__ off,
    int nc, int n, int e) {
  int t = threadIdx.x;
  int v = (t < nc) ? ccnt[t * 16] : 0;
  int incl = v;
#pragma unroll
  for (int ofs = 1; ofs < 64; ofs <<= 1) {
    int w = __shfl_up(incl, ofs);
    if (t >= ofs) incl += w;
  }
  int excl = incl - v;
  if (t < nc) { coff[t] = excl; ccur[t * 16] = excl; }
  if (t == nc - 1) coff[nc] = incl;
  if (t == 0) off[n] = e;
}

// LDS-staged partition: sort a 4096-edge tile by coarse bucket in LDS, reserve
// a global range per bucket with ONE atomic, stream out contiguous segments.
__global__ __launch_bounds__(256) void coarse_partition_kernel(const int* __restrict__ src,
    const int* __restrict__ dst, int* __restrict__ ccur,
    unsigned int* __restrict__ packed, int e) {
  __shared__ unsigned int stage[TILE];
  __shared__ unsigned char bid[TILE];
  __shared__ int hist[NCMAX], excl[NCMAX], gbase[NCMAX], lcur[NCMAX];
  int ntiles = (e + TILE - 1) / TILE;
  for (int tile = blockIdx.x; tile < ntiles; tile += gridDim.x) {
    int i0 = tile * TILE;
    int cnt = e - i0; if (cnt > TILE) cnt = TILE;
    if (threadIdx.x < NCMAX) hist[threadIdx.x] = 0;
    __syncthreads();
    int myS[16], myD[16];
#pragma unroll
    for (int k = 0; k < 16; ++k) {
      int li = threadIdx.x + k * 256;
      if (li < cnt) {
        myS[k] = src[i0 + li];
        myD[k] = dst[i0 + li];
        atomicAdd(&hist[myD[k] >> CSHIFT], 1);
      }
    }
    __syncthreads();
    if (threadIdx.x < NCMAX) {  // wave 0: scan 64 buckets
      int t = threadIdx.x;
      int v = hist[t];
      int incl = v;
#pragma unroll
      for (int ofs = 1; ofs < 64; ofs <<= 1) {
        int w = __shfl_up(incl, ofs);
        if (t >= ofs) incl += w;
      }
      excl[t] = incl - v;
      lcur[t] = incl - v;
    }
    __syncthreads();
#pragma unroll
    for (int k = 0; k < 16; ++k) {
      int li = threadIdx.x + k * 256;
      if (li < cnt) {
        int c = myD[k] >> CSHIFT;
        int p = atomicAdd(&lcur[c], 1);
        stage[p] = (unsigned int)myS[k] | ((unsigned int)(myD[k] & CMASK) << 17);
        bid[p] = (unsigned char)c;
      }
    }
    __syncthreads();
    if (threadIdx.x < NCMAX) {
      int t = threadIdx.x;
      int cc = lcur[t] - excl[t];
      gbase[t] = cc ? atomicAdd(&ccur[t * 16], cc) : 0;
    }
    __syncthreads();
    for (int i = threadIdx.x; i < cnt; i += 256) {
      int c = bid[i];
      packed[gbase[c] + (i - excl[c])] = stage[i];
    }
    __syncthreads();  // protect hist/stage reuse
  }
}

// one block per coarse bucket: counting sort 2048 node sub-buckets -> csr, off, dinv.
__global__ __launch_bounds__(512) void csr_fine_kernel(const unsigned int* __restrict__ packed,
    const int* __restrict__ coff, int* __restrict__ off, float* __restrict__ dinv,
    int* __restrict__ csr, int n) {
  __shared__ int lh[2048];
  __shared__ int lsum[512];
  int b = blockIdx.x;
  int t = threadIdx.x;
  int e0 = coff[b], e1 = coff[b + 1];
  int node0 = b << CSHIFT;
  for (int i = t; i < 2048; i += 512) lh[i] = 0;
  __syncthreads();
  for (int i = e0 + t; i < e1; i += 512) atomicAdd(&lh[packed[i] >> 17], 1);
  __syncthreads();
  int base = t * 4;
  int v0 = lh[base], v1 = lh[base + 1], v2 = lh[base + 2], v3 = lh[base + 3];
  int tsum = v0 + v1 + v2 + v3;
  lsum[t] = tsum;
  __syncthreads();
  for (int ofs = 1; ofs < 512; ofs <<= 1) {
    int add = (t >= ofs) ? lsum[t - ofs] : 0;
    __syncthreads();
    lsum[t] += add;
    __syncthreads();
  }
  int ex = lsum[t] - tsum;
  int exc0 = ex, exc1 = ex + v0, exc2 = ex + v0 + v1, exc3 = ex + v0 + v1 + v2;
  lh[base] = exc0; lh[base + 1] = exc1; lh[base + 2] = exc2; lh[base + 3] = exc3;
  int node = node0 + base;
  if (node < n)     { off[node]     = e0 + exc0; dinv[node]     = rsqrtf((float)(v0 + 1)); }
  if (node + 1 < n) { off[node + 1] = e0 + exc1; dinv[node + 1] = rsqrtf((float)(v1 + 1)); }
  if (node + 2 < n) { off[node + 2] = e0 + exc2; dinv[node + 2] = rsqrtf((float)(v2 + 1)); }
  if (node + 3 < n) { off[node + 3] = e0 + exc3; dinv[node + 3] = rsqrtf((float)(v3 + 1)); }
  __syncthreads();
  for (int i = e0 + t; i < e1; i += 512) {
    unsigned int p = packed[i];
    int nl = p >> 17;
    int pos = atomicAdd(&lh[nl], 1);
    csr[e0 + pos] = (int)(p & 0x1FFFFu);
  }
}

// ---------- h1' = dinv * (x @ W1) via MFMA, output bf16 ----------
// 64-row tile per block, 4 waves; wave w owns rows w*16..w*16+15 (full 64 cols).
// xs: x-tile as bf16 [64 rows][128 k] packed in uints, 16B-slot XOR swizzle.
// wt: W transposed+packed bf16 [64 cols][128 k], same swizzle.
// Per wave: 4 A-frags + 16 B-frags (b128 reads) + 16 mfma_f32_16x16x32_bf16.
// A layout: row=l&15, k=(l>>4)*8+j. B: col=l&15, k=(l>>4)*8+j. D: col=l&15,
// row=(l>>4)*4+reg (m89-verified).
__global__ __launch_bounds__(256) void gemm1_kernel(const float* __restrict__ x,
    const float* __restrict__ W1, const float* __restrict__ dinv,
    unsigned int* __restrict__ h1, int n) {
  __shared__ unsigned int xs[64 * 64];  // 16 KB
  __shared__ unsigned int wt[64 * 64];  // 16 KB
  // W1[k][c] -> wt[c][k-pairs], bf16-packed, swizzled
  for (int i = threadIdx.x; i < 4096; i += 256) {
    int c = i & 63, kp = i >> 6;             // kp = k-pair index 0..63
    float a = W1[(2 * kp) * 64 + c];
    float b = W1[(2 * kp + 1) * 64 + c];
    int slot = kp >> 2;                      // 16B slot (4 uints)
    int slotS = slot ^ (c & 7);
    wt[c * 64 + slotS * 4 + (kp & 3)] = pack_bf16(a, b);
  }
  int row0 = blockIdx.x * 64;
  int nrow = n - row0; if (nrow > 64) nrow = 64;
  // x tile -> bf16, swizzled
  for (int i = threadIdx.x; i < 64 * 32; i += 256) {
    int r = i >> 5, q = i & 31;              // q = float4 quad (k = 4q..4q+3)
    float4 v = make_float4(0.f, 0.f, 0.f, 0.f);
    if (r < nrow) v = ((const float4*)(x + (size_t)(row0 + r) * 128))[q];
    int slot = q >> 1;
    int slotS = slot ^ (r & 7);
    int bi = r * 64 + slotS * 4 + (q & 1) * 2;
    xs[bi]     = pack_bf16(v.x, v.y);
    xs[bi + 1] = pack_bf16(v.z, v.w);
  }
  __syncthreads();
  int lane = threadIdx.x & 63;
  int w = threadIdx.x >> 6;
  int rl = lane & 15;
  int g = lane >> 4;
  f32x4 acc[4];
#pragma unroll
  for (int i = 0; i < 4; ++i) acc[i] = (f32x4){0.f, 0.f, 0.f, 0.f};
#pragma unroll
  for (int ks = 0; ks < 4; ++ks) {
    int as = ((ks * 4 + g) ^ (rl & 7)) * 4;
    bf16x8 af = *reinterpret_cast<const bf16x8*>(&xs[(w * 16 + rl) * 64 + as]);
#pragma unroll
    for (int nt = 0; nt < 4; ++nt) {
      int col = nt * 16 + rl;
      int bs = ((ks * 4 + g) ^ (col & 7)) * 4;
      bf16x8 bfr = *reinterpret_cast<const bf16x8*>(&wt[col * 64 + bs]);
      acc[nt] = __builtin_amdgcn_mfma_f32_16x16x32_bf16(af, bfr, acc[nt], 0, 0, 0);
    }
  }
  // epilogue: reg i -> row_local = g*4+i, col = nt*16+rl; scale by dinv, pack pairs
#pragma unroll
  for (int i = 0; i < 4; ++i) {
    int row = row0 + w * 16 + g * 4 + i;
    float dv = (row < n) ? dinv[row] : 0.f;
#pragma unroll
    for (int nt = 0; nt < 4; ++nt) {
      float val = dv * acc[nt][i];
      float pv = __shfl_xor(val, 1);
      if (!(lane & 1) && row < n) {
        h1[(size_t)row * 32 + nt * 8 + (rl >> 1)] = pack_bf16(val, pv);
      }
    }
  }
}

// ---------- aggregation ----------
// 16 edge-slots x 4 feature-lanes per wave. h rows dinv-prefolded (h'=dinv*h).
// acc = h'[node] + sum_{e:dst=node} h'[src];  result = dinv[node]*acc.
// Recursive-halving shfl reduce leaves ONE feature per lane (static reg indices).
// EPI=1: out = bf16( dinv * tanh(result + bias) ); EPI=0: out = bf16(result).
template <int EPI>
__global__ __launch_bounds__(256) void agg_kernel(const uint4* __restrict__ h4,
    const int* __restrict__ off, const int* __restrict__ csr,
    const float* __restrict__ dinv, const float* __restrict__ bias,
    unsigned int* __restrict__ out, int n) {
  int node = blockIdx.x * 4 + (threadIdx.x >> 6);
  if (node >= n) return;
  int lane = threadIdx.x & 63;
  int j = lane >> 2;   // edge slot 0..15
  int l = lane & 3;    // feature quarter (16 bf16 = 32B = 2 uint4)
  float acc[16];
#pragma unroll
  for (int i = 0; i < 16; ++i) acc[i] = 0.f;
  if (j == 0) {  // self loop
    uint4 a = h4[(size_t)node * 8 + l * 2];
    uint4 b = h4[(size_t)node * 8 + l * 2 + 1];
    add8(acc, a);
    add8(acc + 8, b);
  }
  int e1 = off[node + 1];
  for (int ee = off[node] + j; ee < e1; ee += 16) {
    int s = __builtin_nontemporal_load(&csr[ee]);
    uint4 a = h4[(size_t)s * 8 + l * 2];
    uint4 b = h4[(size_t)s * 8 + l * 2 + 1];
    add8(acc, a);
    add8(acc + 8, b);
  }
  // recursive-halving reduce over the 16 slots; feature count 16 -> 1
#pragma unroll
  for (int i = 0; i < 8; ++i) {
    float tlo = acc[i]     + __shfl_xor(acc[i], 4);
    float thi = acc[i + 8] + __shfl_xor(acc[i + 8], 4);
    acc[i] = (j & 1) ? thi : tlo;
  }
#pragma unroll
  for (int i = 0; i < 4; ++i) {
    float tlo = acc[i]     + __shfl_xor(acc[i], 8);
    float thi = acc[i + 4] + __shfl_xor(acc[i + 4], 8);
    acc[i] = (j & 2) ? thi : tlo;
  }
#pragma unroll
  for (int i = 0; i < 2; ++i) {
    float tlo = acc[i]     + __shfl_xor(acc[i], 16);
    float thi = acc[i + 2] + __shfl_xor(acc[i + 2], 16);
    acc[i] = (j & 4) ? thi : tlo;
  }
  float a0, a1;
  a0 = acc[0] + __shfl_xor(acc[0], 32);
  a1 = acc[1] + __shfl_xor(acc[1], 32);
  float a = (j & 8) ? a1 : a0;
  // this lane now owns feature f = l*16 + j0*8 + j1*4 + j2*2 + j3
  int f = l * 16 + ((j & 1) << 3) + ((j & 2) << 1) + ((j >> 2) & 1) * 2 + ((j >> 3) & 1);
  float di = dinv[node];
  float val;
  if (EPI) {
    val = di * tanhf(fmaf(di, a, bias[f]));
  } else {
    val = di * a;
  }
  // pack feature pairs (f even with f+1, partner lane = lane^32) and store
  float pv = __shfl_xor(val, 32);
  if (!(j & 8)) {  // f even
    unsigned int w = pack_bf16(val, pv);
    int half = l * 8 + ((j & 1) << 2) + (j & 2) + ((j >> 2) & 1);  // f/2
    out[(size_t)node * 32 + half] = w;
  }
}

// ---------- final: mean/logvar GEMMs + reparam ----------
__global__ __launch_bounds__(256) void final_kernel(const unsigned int* __restrict__ aggb,
    const float* __restrict__ Wm, const float* __restrict__ bm,
    const float* __restrict__ Wv, const float* __restrict__ bv,
    const float* __restrict__ noise, float* __restrict__ outZ,
    float* __restrict__ outM, float* __restrict__ outLv, int n) {
  __shared__ float WmS[64 * 32];
  __shared__ float WvS[64 * 32];
  __shared__ float aggS[64 * 68];  // stride 68 breaks bank conflicts
  for (int i = threadIdx.x; i < 64 * 8; i += 256) {
    ((float4*)WmS)[i] = ((const float4*)Wm)[i];
    ((float4*)WvS)[i] = ((const float4*)Wv)[i];
  }
  int row0 = blockIdx.x * 64;
  int nrow = n - row0; if (nrow > 64) nrow = 64;
  for (int i = threadIdx.x; i < 64 * 16; i += 256) {
    int r = i >> 4, g = i & 15;
    uint2 u = make_uint2(0u, 0u);
    if (r < nrow) u = ((const uint2*)aggb)[(size_t)(row0 + r) * 16 + g];
    float* d = &aggS[r * 68 + g * 4];
    d[0] = __uint_as_float(u.x << 16);
    d[1] = __uint_as_float(u.x & 0xFFFF0000u);
    d[2] = __uint_as_float(u.y << 16);
    d[3] = __uint_as_float(u.y & 0xFFFF0000u);
  }
  __syncthreads();
  int c4 = (threadIdx.x & 7) * 4;
  int r2 = (threadIdx.x >> 3) * 2;
  float4 am[2], av[2];
#pragma unroll
  for (int i = 0; i < 2; ++i) {
    am[i] = make_float4(0.f, 0.f, 0.f, 0.f);
    av[i] = make_float4(0.f, 0.f, 0.f, 0.f);
  }
#pragma unroll 4
  for (int kq = 0; kq < 16; ++kq) {
    float4 xa[2], wm[4], wv[4];
#pragma unroll
    for (int i = 0; i < 2; ++i) xa[i] = *(const float4*)&aggS[(r2 + i) * 68 + kq * 4];
#pragma unroll
    for (int q = 0; q < 4; ++q) {
      wm[q] = *(const float4*)&WmS[(kq * 4 + q) * 32 + c4];
      wv[q] = *(const float4*)&WvS[(kq * 4 + q) * 32 + c4];
    }
#pragma unroll
    for (int i = 0; i < 2; ++i) {
      fma4(am[i], xa[i].x, wm[0]); fma4(am[i], xa[i].y, wm[1]);
      fma4(am[i], xa[i].z, wm[2]); fma4(am[i], xa[i].w, wm[3]);
      fma4(av[i], xa[i].x, wv[0]); fma4(av[i], xa[i].y, wv[1]);
      fma4(av[i], xa[i].z, wv[2]); fma4(av[i], xa[i].w, wv[3]);
    }
  }
  float4 bmv = *(const float4*)&bm[c4];
  float4 bvv = *(const float4*)&bv[c4];
#pragma unroll
  for (int i = 0; i < 2; ++i) {
    int row = row0 + r2 + i;
    if (row < n) {
      float4 m = am[i]; m.x += bmv.x; m.y += bmv.y; m.z += bmv.z; m.w += bmv.w;
      float4 v = av[i]; v.x += bvv.x; v.y += bvv.y; v.z += bvv.z; v.w += bvv.w;
      size_t oi = (size_t)row * 8 + (threadIdx.x & 7);
      float4 nz = ((const float4*)noise)[oi];
      float4 z;
      z.x = fmaf(nz.x, expf(0.5f * v.x), m.x);
      z.y = fmaf(nz.y, expf(0.5f * v.y), m.y);
      z.z = fmaf(nz.z, expf(0.5f * v.z), m.z);
      z.w = fmaf(nz.w, expf(0.5f * v.w), m.w);
      ((float4*)outZ)[oi] = z;
      ((float4*)outM)[oi] = m;
      ((float4*)outLv)[oi] = v;
    }
  }
}

// ---------- launch ----------

extern "C" void kernel_launch(void* const* d_in, const int* in_sizes, int n_in,
                              void* d_out, int out_size, void* d_ws, size_t ws_size,
                              hipStream_t stream) {
  const float* x     = (const float*)d_in[0];
  const int*   edge  = (const int*)d_in[1];
  const float* W1    = (const float*)d_in[2];
  const float* b1    = (const float*)d_in[3];
  const float* Wm    = (const float*)d_in[4];
  const float* bm    = (const float*)d_in[5];
  const float* Wv    = (const float*)d_in[6];
  const float* bv    = (const float*)d_in[7];
  const float* noise = (const float*)d_in[8];
  int n = in_sizes[0] / 128;
  int e = in_sizes[1] / 2;
  const int* src = edge;
  const int* dst = edge + e;
  int nc = (n + CMASK) >> CSHIFT;   // 49 coarse buckets of 2048 nodes

  // workspace layout (int units, 16B-aligned segments)
  int* ccnt = (int*)d_ws;                          // NCMAX*16 (1 per 64B line)
  int* ccur = ccnt + NCMAX * 16;                   // NCMAX*16
  int* coff = ccur + NCMAX * 16;                   // NCMAX+1 (+pad)
  int* off  = coff + (NCMAX + 4);                  // n+1 (+pad)
  float* dinv = (float*)(off + ((n + 4) & ~3));    // n
  unsigned int* packed = (unsigned int*)(dinv + ((n + 3) & ~3)); // e
  int* csr  = (int*)(packed + ((e + 3) & ~3));     // e
  unsigned int* h1b = (unsigned int*)(csr + ((e + 3) & ~3)); // n*32 (bf16 h1')
  unsigned int* hb  = h1b + (size_t)n * 32;                  // n*32 (bf16 h')
  unsigned int* aggb = hb + (size_t)n * 32;                  // n*32 (bf16 agg2)

  float* outZ  = (float*)d_out;
  float* outM  = outZ + (size_t)n * 32;
  float* outLv = outM + (size_t)n * 32;

  int ntiles = (e + TILE - 1) / TILE;

  zero_kernel<<<(NCMAX * 16 + 255) / 256, 256, 0, stream>>>(ccnt, NCMAX * 16);
  coarse_hist_kernel<<<256, 256, 0, stream>>>(dst, ccnt, e);
  coarse_scan_kernel<<<1, 64, 0, stream>>>(ccnt, coff, ccur, off, nc, n, e);
  coarse_partition_kernel<<<ntiles, 256, 0, stream>>>(src, dst, ccur, packed, e);
  csr_fine_kernel<<<nc, 512, 0, stream>>>(packed, coff, off, dinv, csr, n);
  gemm1_kernel<<<(n + 63) / 64, 256, 0, stream>>>(x, W1, dinv, h1b, n);
  agg_kernel<1><<<(n + 3) / 4, 256, 0, stream>>>((const uint4*)h1b, off, csr, dinv, b1, hb, n);
  agg_kernel<0><<<(n + 3) / 4, 256, 0, stream>>>((const uint4*)hb, off, csr, dinv, b1, aggb, n);
  final_kernel<<<(n + 63) / 64, 256, 0, stream>>>(aggb, Wm, bm, Wv, bv, noise, outZ, outM, outLv, n);
}

// Round 11
// 192.758 us; speedup vs baseline: 1.4938x; 1.0146x over previous
//
#include <hip/hip_runtime.h>
#include <math.h>

#define TILE 4096          // edges per partition tile
#define CSHIFT 11          // coarse bucket = dst >> 11  (2048 nodes)
#define CMASK 2047
#define NCMAX 64

typedef __attribute__((ext_vector_type(8))) short bf16x8;   // 8 bf16 (4 VGPRs)
typedef __attribute__((ext_vector_type(4))) float f32x4;

// ---------- helpers ----------

__device__ __forceinline__ unsigned int pack_bf16(float a, float b) {
  unsigned int ua = __float_as_uint(a);
  ua += 0x7FFFu + ((ua >> 16) & 1u);
  unsigned int ub = __float_as_uint(b);
  ub += 0x7FFFu + ((ub >> 16) & 1u);
  return (ua >> 16) | (ub & 0xFFFF0000u);
}

// acc[0..7] += bf16x8(hv)
__device__ __forceinline__ void add8(float* acc, uint4 hv) {
  unsigned int u[4] = {hv.x, hv.y, hv.z, hv.w};
#pragma unroll
  for (int i = 0; i < 4; ++i) {
    acc[2 * i]     += __uint_as_float(u[i] << 16);
    acc[2 * i + 1] += __uint_as_float(u[i] & 0xFFFF0000u);
  }
}

__device__ __forceinline__ void fma4(float4& acc, float s, const float4& w) {
  acc.x = fmaf(s, w.x, acc.x);
  acc.y = fmaf(s, w.y, acc.y);
  acc.z = fmaf(s, w.z, acc.z);
  acc.w = fmaf(s, w.w, acc.w);
}

// ---------- CSR build: two-level LDS-staged split ----------

__global__ void zero_kernel(int* __restrict__ p, int n) {
  int i = blockIdx.x * blockDim.x + threadIdx.x;
  if (i < n) p[i] = 0;
}

__global__ __launch_bounds__(256) void coarse_hist_kernel(const int* __restrict__ dst,
    int* __restrict__ ccnt, int e) {
  __shared__ int h[NCMAX];
  if (threadIdx.x < NCMAX) h[threadIdx.x] = 0;
  __syncthreads();
  for (int i = blockIdx.x * 256 + threadIdx.x; i < e; i += gridDim.x * 256)
    atomicAdd(&h[dst[i] >> CSHIFT], 1);
  __syncthreads();
  if (threadIdx.x < NCMAX && h[threadIdx.x])
    atomicAdd(&ccnt[threadIdx.x * 16], h[threadIdx.x]);
}

// single wave: exclusive scan of nc coarse counts; init cursors; off[n]=e
__global__ __launch_bounds__(64) void coarse_scan_kernel(const int* __restrict__ ccnt,
    int* __restrict__ coff, int* __restrict__ ccur, int* __restrict__ off,
    int nc, int n, int e) {
  int t = threadIdx.x;
  int v = (t < nc) ? ccnt[t * 16] : 0;
  int incl = v;
#pragma unroll
  for (int ofs = 1; ofs < 64; ofs <<= 1) {
    int w = __shfl_up(incl, ofs);
    if (t >= ofs) incl += w;
  }
  int excl = incl - v;
  if (t < nc) { coff[t] = excl; ccur[t * 16] = excl; }
  if (t == nc - 1) coff[nc] = incl;
  if (t == 0) off[n] = e;
}

// LDS-staged partition: sort a 4096-edge tile by coarse bucket in LDS, reserve
// a global range per bucket with ONE atomic, stream out contiguous segments.
__global__ __launch_bounds__(256) void coarse_partition_kernel(const int* __restrict__ src,
    const int* __restrict__ dst, int* __restrict__ ccur,
    unsigned int* __restrict__ packed, int e) {
  __shared__ unsigned int stage[TILE];
  __shared__ unsigned char bid[TILE];
  __shared__ int hist[NCMAX], excl[NCMAX], gbase[NCMAX], lcur[NCMAX];
  int ntiles = (e + TILE - 1) / TILE;
  for (int tile = blockIdx.x; tile < ntiles; tile += gridDim.x) {
    int i0 = tile * TILE;
    int cnt = e - i0; if (cnt > TILE) cnt = TILE;
    if (threadIdx.x < NCMAX) hist[threadIdx.x] = 0;
    __syncthreads();
    int myS[16], myD[16];
#pragma unroll
    for (int k = 0; k < 16; ++k) {
      int li = threadIdx.x + k * 256;
      if (li < cnt) {
        myS[k] = src[i0 + li];
        myD[k] = dst[i0 + li];
        atomicAdd(&hist[myD[k] >> CSHIFT], 1);
      }
    }
    __syncthreads();
    if (threadIdx.x < NCMAX) {  // wave 0: scan 64 buckets
      int t = threadIdx.x;
      int v = hist[t];
      int incl = v;
#pragma unroll
      for (int ofs = 1; ofs < 64; ofs <<= 1) {
        int w = __shfl_up(incl, ofs);
        if (t >= ofs) incl += w;
      }
      excl[t] = incl - v;
      lcur[t] = incl - v;
    }
    __syncthreads();
#pragma unroll
    for (int k = 0; k < 16; ++k) {
      int li = threadIdx.x + k * 256;
      if (li < cnt) {
        int c = myD[k] >> CSHIFT;
        int p = atomicAdd(&lcur[c], 1);
        stage[p] = (unsigned int)myS[k] | ((unsigned int)(myD[k] & CMASK) << 17);
        bid[p] = (unsigned char)c;
      }
    }
    __syncthreads();
    if (threadIdx.x < NCMAX) {
      int t = threadIdx.x;
      int cc = lcur[t] - excl[t];
      gbase[t] = cc ? atomicAdd(&ccur[t * 16], cc) : 0;
    }
    __syncthreads();
    for (int i = threadIdx.x; i < cnt; i += 256) {
      int c = bid[i];
      packed[gbase[c] + (i - excl[c])] = stage[i];
    }
    __syncthreads();  // protect hist/stage reuse
  }
}

// one block per coarse bucket: counting sort 2048 node sub-buckets -> csr, off, dinv.
__global__ __launch_bounds__(512) void csr_fine_kernel(const unsigned int* __restrict__ packed,
    const int* __restrict__ coff, int* __restrict__ off, float* __restrict__ dinv,
    int* __restrict__ csr, int n) {
  __shared__ int lh[2048];
  __shared__ int lsum[512];
  int b = blockIdx.x;
  int t = threadIdx.x;
  int e0 = coff[b], e1 = coff[b + 1];
  int node0 = b << CSHIFT;
  for (int i = t; i < 2048; i += 512) lh[i] = 0;
  __syncthreads();
  for (int i = e0 + t; i < e1; i += 512) atomicAdd(&lh[packed[i] >> 17], 1);
  __syncthreads();
  int base = t * 4;
  int v0 = lh[base], v1 = lh[base + 1], v2 = lh[base + 2], v3 = lh[base + 3];
  int tsum = v0 + v1 + v2 + v3;
  lsum[t] = tsum;
  __syncthreads();
  for (int ofs = 1; ofs < 512; ofs <<= 1) {
    int add = (t >= ofs) ? lsum[t - ofs] : 0;
    __syncthreads();
    lsum[t] += add;
    __syncthreads();
  }
  int ex = lsum[t] - tsum;
  int exc0 = ex, exc1 = ex + v0, exc2 = ex + v0 + v1, exc3 = ex + v0 + v1 + v2;
  lh[base] = exc0; lh[base + 1] = exc1; lh[base + 2] = exc2; lh[base + 3] = exc3;
  int node = node0 + base;
  if (node < n)     { off[node]     = e0 + exc0; dinv[node]     = rsqrtf((float)(v0 + 1)); }
  if (node + 1 < n) { off[node + 1] = e0 + exc1; dinv[node + 1] = rsqrtf((float)(v1 + 1)); }
  if (node + 2 < n) { off[node + 2] = e0 + exc2; dinv[node + 2] = rsqrtf((float)(v2 + 1)); }
  if (node + 3 < n) { off[node + 3] = e0 + exc3; dinv[node + 3] = rsqrtf((float)(v3 + 1)); }
  __syncthreads();
  for (int i = e0 + t; i < e1; i += 512) {
    unsigned int p = packed[i];
    int nl = p >> 17;
    int pos = atomicAdd(&lh[nl], 1);
    csr[e0 + pos] = (int)(p & 0x1FFFFu);
  }
}

// ---------- h1' = dinv * (x @ W1) via MFMA, output bf16 ----------
// 64-row tile per block, 4 waves; wave w owns rows w*16..w*16+15 (full 64 cols).
// xs: x-tile as bf16 [64 rows][128 k] packed in uints, 16B-slot XOR swizzle.
// wt: W transposed+packed bf16 [64 cols][128 k], same swizzle.
__global__ __launch_bounds__(256) void gemm1_kernel(const float* __restrict__ x,
    const float* __restrict__ W1, const float* __restrict__ dinv,
    unsigned int* __restrict__ h1, int n) {
  __shared__ unsigned int xs[64 * 64];  // 16 KB
  __shared__ unsigned int wt[64 * 64];  // 16 KB
  // W1[k][c] -> wt[c][k-pairs], bf16-packed, swizzled
  for (int i = threadIdx.x; i < 4096; i += 256) {
    int c = i & 63, kp = i >> 6;             // kp = k-pair index 0..63
    float a = W1[(2 * kp) * 64 + c];
    float b = W1[(2 * kp + 1) * 64 + c];
    int slot = kp >> 2;                      // 16B slot (4 uints)
    int slotS = slot ^ (c & 7);
    wt[c * 64 + slotS * 4 + (kp & 3)] = pack_bf16(a, b);
  }
  int row0 = blockIdx.x * 64;
  int nrow = n - row0; if (nrow > 64) nrow = 64;
  // x tile -> bf16, swizzled
  for (int i = threadIdx.x; i < 64 * 32; i += 256) {
    int r = i >> 5, q = i & 31;              // q = float4 quad (k = 4q..4q+3)
    float4 v = make_float4(0.f, 0.f, 0.f, 0.f);
    if (r < nrow) v = ((const float4*)(x + (size_t)(row0 + r) * 128))[q];
    int slot = q >> 1;
    int slotS = slot ^ (r & 7);
    int bi = r * 64 + slotS * 4 + (q & 1) * 2;
    xs[bi]     = pack_bf16(v.x, v.y);
    xs[bi + 1] = pack_bf16(v.z, v.w);
  }
  __syncthreads();
  int lane = threadIdx.x & 63;
  int w = threadIdx.x >> 6;
  int rl = lane & 15;
  int g = lane >> 4;
  f32x4 acc[4];
#pragma unroll
  for (int i = 0; i < 4; ++i) acc[i] = (f32x4){0.f, 0.f, 0.f, 0.f};
#pragma unroll
  for (int ks = 0; ks < 4; ++ks) {
    int as = ((ks * 4 + g) ^ (rl & 7)) * 4;
    bf16x8 af = *reinterpret_cast<const bf16x8*>(&xs[(w * 16 + rl) * 64 + as]);
#pragma unroll
    for (int nt = 0; nt < 4; ++nt) {
      int col = nt * 16 + rl;
      int bs = ((ks * 4 + g) ^ (col & 7)) * 4;
      bf16x8 bfr = *reinterpret_cast<const bf16x8*>(&wt[col * 64 + bs]);
      acc[nt] = __builtin_amdgcn_mfma_f32_16x16x32_bf16(af, bfr, acc[nt], 0, 0, 0);
    }
  }
  // epilogue: reg i -> row_local = g*4+i, col = nt*16+rl; scale by dinv, pack pairs
#pragma unroll
  for (int i = 0; i < 4; ++i) {
    int row = row0 + w * 16 + g * 4 + i;
    float dv = (row < n) ? dinv[row] : 0.f;
#pragma unroll
    for (int nt = 0; nt < 4; ++nt) {
      float val = dv * acc[nt][i];
      float pv = __shfl_xor(val, 1);
      if (!(lane & 1) && row < n) {
        h1[(size_t)row * 32 + nt * 8 + (rl >> 1)] = pack_bf16(val, pv);
      }
    }
  }
}

// ---------- aggregation ----------
// 2 nodes x 16 edge-slots x 2 feature-lanes per wave. h rows dinv-prefolded.
// Each lane loads 64B (4 independent uint4) of the gathered row -> 4KB of
// h-gather in flight per wave (2x round 10). Static recursive-halving reduce
// over slot bits; every lane ends with 2 features -> fully coalesced write.
// EPI=1: out = bf16( dinv * tanh(result + bias) ); EPI=0: out = bf16(result).
template <int EPI>
__global__ __launch_bounds__(256) void agg_kernel(const uint4* __restrict__ h4,
    const int* __restrict__ off, const int* __restrict__ csr,
    const float* __restrict__ dinv, const float* __restrict__ bias,
    unsigned int* __restrict__ out, int n) {
  int lane = threadIdx.x & 63;
  int nd = lane >> 5;            // which of the wave's 2 nodes
  int j  = (lane >> 1) & 15;     // edge slot 0..15
  int fl = lane & 1;             // feature half (32 features = 64B = 4 uint4)
  int node = blockIdx.x * 8 + (threadIdx.x >> 6) * 2 + nd;
  bool valid = node < n;
  float acc[32];
#pragma unroll
  for (int i = 0; i < 32; ++i) acc[i] = 0.f;
  if (valid) {
    if (j == 0) {  // self loop
      const uint4* hp = &h4[(size_t)node * 8 + fl * 4];
      uint4 a = hp[0], b = hp[1], c = hp[2], d = hp[3];
      add8(acc, a); add8(acc + 8, b); add8(acc + 16, c); add8(acc + 24, d);
    }
    int e1 = off[node + 1];
    for (int ee = off[node] + j; ee < e1; ee += 16) {
      int s = __builtin_nontemporal_load(&csr[ee]);
      const uint4* hp = &h4[(size_t)s * 8 + fl * 4];
      uint4 a = hp[0], b = hp[1], c = hp[2], d = hp[3];
      add8(acc, a); add8(acc + 8, b); add8(acc + 16, c); add8(acc + 24, d);
    }
  }
  // reduce over slot bits (lane bits 1..4); features 32 -> 2 per lane
#pragma unroll
  for (int i = 0; i < 16; ++i) {
    float tlo = acc[i]      + __shfl_xor(acc[i], 2);
    float thi = acc[i + 16] + __shfl_xor(acc[i + 16], 2);
    acc[i] = (j & 1) ? thi : tlo;
  }
#pragma unroll
  for (int i = 0; i < 8; ++i) {
    float tlo = acc[i]     + __shfl_xor(acc[i], 4);
    float thi = acc[i + 8] + __shfl_xor(acc[i + 8], 4);
    acc[i] = (j & 2) ? thi : tlo;
  }
#pragma unroll
  for (int i = 0; i < 4; ++i) {
    float tlo = acc[i]     + __shfl_xor(acc[i], 8);
    float thi = acc[i + 4] + __shfl_xor(acc[i + 4], 8);
    acc[i] = (j & 4) ? thi : tlo;
  }
#pragma unroll
  for (int i = 0; i < 2; ++i) {
    float tlo = acc[i]     + __shfl_xor(acc[i], 16);
    float thi = acc[i + 2] + __shfl_xor(acc[i + 2], 16);
    acc[i] = (j & 8) ? thi : tlo;
  }
  // lane owns features f0, f0+1 with f0 = fl*32 + 16*b0 + 8*b1 + 4*b2 + 2*b3
  int b0 = j & 1, b1 = (j >> 1) & 1, b2 = (j >> 2) & 1, b3 = (j >> 3) & 1;
  int f0 = fl * 32 + 16 * b0 + 8 * b1 + 4 * b2 + 2 * b3;
  if (valid) {
    float di = dinv[node];
    float v0, v1;
    if (EPI) {
      v0 = di * tanhf(fmaf(di, acc[0], bias[f0]));
      v1 = di * tanhf(fmaf(di, acc[1], bias[f0 + 1]));
    } else {
      v0 = di * acc[0];
      v1 = di * acc[1];
    }
    out[(size_t)node * 32 + (f0 >> 1)] = pack_bf16(v0, v1);
  }
}

// ---------- final: mean/logvar GEMMs + reparam ----------
__global__ __launch_bounds__(256) void final_kernel(const unsigned int* __restrict__ aggb,
    const float* __restrict__ Wm, const float* __restrict__ bm,
    const float* __restrict__ Wv, const float* __restrict__ bv,
    const float* __restrict__ noise, float* __restrict__ outZ,
    float* __restrict__ outM, float* __restrict__ outLv, int n) {
  __shared__ float WmS[64 * 32];
  __shared__ float WvS[64 * 32];
  __shared__ float aggS[64 * 68];  // stride 68 breaks bank conflicts
  for (int i = threadIdx.x; i < 64 * 8; i += 256) {
    ((float4*)WmS)[i] = ((const float4*)Wm)[i];
    ((float4*)WvS)[i] = ((const float4*)Wv)[i];
  }
  int row0 = blockIdx.x * 64;
  int nrow = n - row0; if (nrow > 64) nrow = 64;
  for (int i = threadIdx.x; i < 64 * 16; i += 256) {
    int r = i >> 4, g = i & 15;
    uint2 u = make_uint2(0u, 0u);
    if (r < nrow) u = ((const uint2*)aggb)[(size_t)(row0 + r) * 16 + g];
    float* d = &aggS[r * 68 + g * 4];
    d[0] = __uint_as_float(u.x << 16);
    d[1] = __uint_as_float(u.x & 0xFFFF0000u);
    d[2] = __uint_as_float(u.y << 16);
    d[3] = __uint_as_float(u.y & 0xFFFF0000u);
  }
  __syncthreads();
  int c4 = (threadIdx.x & 7) * 4;
  int r2 = (threadIdx.x >> 3) * 2;
  float4 am[2], av[2];
#pragma unroll
  for (int i = 0; i < 2; ++i) {
    am[i] = make_float4(0.f, 0.f, 0.f, 0.f);
    av[i] = make_float4(0.f, 0.f, 0.f, 0.f);
  }
#pragma unroll 4
  for (int kq = 0; kq < 16; ++kq) {
    float4 xa[2], wm[4], wv[4];
#pragma unroll
    for (int i = 0; i < 2; ++i) xa[i] = *(const float4*)&aggS[(r2 + i) * 68 + kq * 4];
#pragma unroll
    for (int q = 0; q < 4; ++q) {
      wm[q] = *(const float4*)&WmS[(kq * 4 + q) * 32 + c4];
      wv[q] = *(const float4*)&WvS[(kq * 4 + q) * 32 + c4];
    }
#pragma unroll
    for (int i = 0; i < 2; ++i) {
      fma4(am[i], xa[i].x, wm[0]); fma4(am[i], xa[i].y, wm[1]);
      fma4(am[i], xa[i].z, wm[2]); fma4(am[i], xa[i].w, wm[3]);
      fma4(av[i], xa[i].x, wv[0]); fma4(av[i], xa[i].y, wv[1]);
      fma4(av[i], xa[i].z, wv[2]); fma4(av[i], xa[i].w, wv[3]);
    }
  }
  float4 bmv = *(const float4*)&bm[c4];
  float4 bvv = *(const float4*)&bv[c4];
#pragma unroll
  for (int i = 0; i < 2; ++i) {
    int row = row0 + r2 + i;
    if (row < n) {
      float4 m = am[i]; m.x += bmv.x; m.y += bmv.y; m.z += bmv.z; m.w += bmv.w;
      float4 v = av[i]; v.x += bvv.x; v.y += bvv.y; v.z += bvv.z; v.w += bvv.w;
      size_t oi = (size_t)row * 8 + (threadIdx.x & 7);
      float4 nz = ((const float4*)noise)[oi];
      float4 z;
      z.x = fmaf(nz.x, expf(0.5f * v.x), m.x);
      z.y = fmaf(nz.y, expf(0.5f * v.y), m.y);
      z.z = fmaf(nz.z, expf(0.5f * v.z), m.z);
      z.w = fmaf(nz.w, expf(0.5f * v.w), m.w);
      ((float4*)outZ)[oi] = z;
      ((float4*)outM)[oi] = m;
      ((float4*)outLv)[oi] = v;
    }
  }
}

// ---------- launch ----------

extern "C" void kernel_launch(void* const* d_in, const int* in_sizes, int n_in,
                              void* d_out, int out_size, void* d_ws, size_t ws_size,
                              hipStream_t stream) {
  const float* x     = (const float*)d_in[0];
  const int*   edge  = (const int*)d_in[1];
  const float* W1    = (const float*)d_in[2];
  const float* b1    = (const float*)d_in[3];
  const float* Wm    = (const float*)d_in[4];
  const float* bm    = (const float*)d_in[5];
  const float* Wv    = (const float*)d_in[6];
  const float* bv    = (const float*)d_in[7];
  const float* noise = (const float*)d_in[8];
  int n = in_sizes[0] / 128;
  int e = in_sizes[1] / 2;
  const int* src = edge;
  const int* dst = edge + e;
  int nc = (n + CMASK) >> CSHIFT;   // 49 coarse buckets of 2048 nodes

  // workspace layout (int units, 16B-aligned segments)
  int* ccnt = (int*)d_ws;                          // NCMAX*16 (1 per 64B line)
  int* ccur = ccnt + NCMAX * 16;                   // NCMAX*16
  int* coff = ccur + NCMAX * 16;                   // NCMAX+1 (+pad)
  int* off  = coff + (NCMAX + 4);                  // n+1 (+pad)
  float* dinv = (float*)(off + ((n + 4) & ~3));    // n
  unsigned int* packed = (unsigned int*)(dinv + ((n + 3) & ~3)); // e
  int* csr  = (int*)(packed + ((e + 3) & ~3));     // e
  unsigned int* h1b = (unsigned int*)(csr + ((e + 3) & ~3)); // n*32 (bf16 h1')
  unsigned int* hb  = h1b + (size_t)n * 32;                  // n*32 (bf16 h')
  unsigned int* aggb = hb + (size_t)n * 32;                  // n*32 (bf16 agg2)

  float* outZ  = (float*)d_out;
  float* outM  = outZ + (size_t)n * 32;
  float* outLv = outM + (size_t)n * 32;

  int ntiles = (e + TILE - 1) / TILE;

  zero_kernel<<<(NCMAX * 16 + 255) / 256, 256, 0, stream>>>(ccnt, NCMAX * 16);
  coarse_hist_kernel<<<256, 256, 0, stream>>>(dst, ccnt, e);
  coarse_scan_kernel<<<1, 64, 0, stream>>>(ccnt, coff, ccur, off, nc, n, e);
  coarse_partition_kernel<<<ntiles, 256, 0, stream>>>(src, dst, ccur, packed, e);
  csr_fine_kernel<<<nc, 512, 0, stream>>>(packed, coff, off, dinv, csr, n);
  gemm1_kernel<<<(n + 63) / 64, 256, 0, stream>>>(x, W1, dinv, h1b, n);
  agg_kernel<1><<<(n + 7) / 8, 256, 0, stream>>>((const uint4*)h1b, off, csr, dinv, b1, hb, n);
  agg_kernel<0><<<(n + 7) / 8, 256, 0, stream>>>((const uint4*)hb, off, csr, dinv, b1, aggb, n);
  final_kernel<<<(n + 63) / 64, 256, 0, stream>>>(aggb, Wm, bm, Wv, bv, noise, outZ, outM, outLv, n);
}

// Round 12
// 190.631 us; speedup vs baseline: 1.5105x; 1.0112x over previous
//
#include <hip/hip_runtime.h>
#include <math.h>

#define TILE 4096          // edges per partition tile
#define CSHIFT 11          // coarse bucket = dst >> 11  (2048 nodes)
#define CMASK 2047
#define NCMAX 64

typedef __attribute__((ext_vector_type(8))) short bf16x8;   // 8 bf16 (4 VGPRs)
typedef __attribute__((ext_vector_type(4))) float f32x4;
typedef __attribute__((ext_vector_type(2))) float f32x2;

// ---------- helpers ----------

__device__ __forceinline__ unsigned int pack_bf16(float a, float b) {
  unsigned int ua = __float_as_uint(a);
  ua += 0x7FFFu + ((ua >> 16) & 1u);
  unsigned int ub = __float_as_uint(b);
  ub += 0x7FFFu + ((ub >> 16) & 1u);
  return (ua >> 16) | (ub & 0xFFFF0000u);
}

// acc[0..7] += bf16x8(hv)
__device__ __forceinline__ void add8(float* acc, uint4 hv) {
  unsigned int u[4] = {hv.x, hv.y, hv.z, hv.w};
#pragma unroll
  for (int i = 0; i < 4; ++i) {
    acc[2 * i]     += __uint_as_float(u[i] << 16);
    acc[2 * i + 1] += __uint_as_float(u[i] & 0xFFFF0000u);
  }
}

// acc[0..15] += fp8x16(hv)  (e4m3, HW decode)
__device__ __forceinline__ void add16_fp8(float* acc, uint4 hv) {
  unsigned int u[4] = {hv.x, hv.y, hv.z, hv.w};
#pragma unroll
  for (int i = 0; i < 4; ++i) {
    f32x2 lo = __builtin_amdgcn_cvt_pk_f32_fp8(u[i], false);
    f32x2 hi = __builtin_amdgcn_cvt_pk_f32_fp8(u[i], true);
    acc[4 * i + 0] += lo[0];
    acc[4 * i + 1] += lo[1];
    acc[4 * i + 2] += hi[0];
    acc[4 * i + 3] += hi[1];
  }
}

__device__ __forceinline__ void fma4(float4& acc, float s, const float4& w) {
  acc.x = fmaf(s, w.x, acc.x);
  acc.y = fmaf(s, w.y, acc.y);
  acc.z = fmaf(s, w.z, acc.z);
  acc.w = fmaf(s, w.w, acc.w);
}

// ---------- CSR build: two-level LDS-staged split ----------

__global__ void zero_kernel(int* __restrict__ p, int n) {
  int i = blockIdx.x * blockDim.x + threadIdx.x;
  if (i < n) p[i] = 0;
}

// 4 LDS replicas per bucket to cut same-address atomic serialization
__global__ __launch_bounds__(256) void coarse_hist_kernel(const int* __restrict__ dst,
    int* __restrict__ ccnt, int e) {
  __shared__ int h[NCMAX * 4];
  for (int i = threadIdx.x; i < NCMAX * 4; i += 256) h[i] = 0;
  __syncthreads();
  int rep = threadIdx.x & 3;
  for (int i = blockIdx.x * 256 + threadIdx.x; i < e; i += gridDim.x * 256)
    atomicAdd(&h[((dst[i] >> CSHIFT) << 2) | rep], 1);
  __syncthreads();
  for (int i = threadIdx.x; i < NCMAX; i += 256) {
    int s = h[i * 4] + h[i * 4 + 1] + h[i * 4 + 2] + h[i * 4 + 3];
    if (s) atomicAdd(&ccnt[i * 16], s);
  }
}

// single wave: exclusive scan of nc coarse counts; init cursors; off[n]=e
__global__ __launch_bounds__(64) void coarse_scan_kernel(const int* __restrict__ ccnt,
    int* __restrict__ coff, int* __restrict__ ccur, int* __restrict__ off,
    int nc, int n, int e) {
  int t = threadIdx.x;
  int v = (t < nc) ? ccnt[t * 16] : 0;
  int incl = v;
#pragma unroll
  for (int ofs = 1; ofs < 64; ofs <<= 1) {
    int w = __shfl_up(incl, ofs);
    if (t >= ofs) incl += w;
  }
  int excl = incl - v;
  if (t < nc) { coff[t] = excl; ccur[t * 16] = excl; }
  if (t == nc - 1) coff[nc] = incl;
  if (t == 0) off[n] = e;
}

// LDS-staged partition: sort a 4096-edge tile by coarse bucket in LDS, reserve
// a global range per bucket with ONE atomic, stream out contiguous segments.
__global__ __launch_bounds__(256) void coarse_partition_kernel(const int* __restrict__ src,
    const int* __restrict__ dst, int* __restrict__ ccur,
    unsigned int* __restrict__ packed, int e) {
  __shared__ unsigned int stage[TILE];
  __shared__ unsigned char bid[TILE];
  __shared__ int hist[NCMAX], excl[NCMAX], gbase[NCMAX], lcur[NCMAX];
  int ntiles = (e + TILE - 1) / TILE;
  for (int tile = blockIdx.x; tile < ntiles; tile += gridDim.x) {
    int i0 = tile * TILE;
    int cnt = e - i0; if (cnt > TILE) cnt = TILE;
    if (threadIdx.x < NCMAX) hist[threadIdx.x] = 0;
    __syncthreads();
    int myS[16], myD[16];
#pragma unroll
    for (int k = 0; k < 16; ++k) {
      int li = threadIdx.x + k * 256;
      if (li < cnt) {
        myS[k] = src[i0 + li];
        myD[k] = dst[i0 + li];
        atomicAdd(&hist[myD[k] >> CSHIFT], 1);
      }
    }
    __syncthreads();
    if (threadIdx.x < NCMAX) {  // wave 0: scan 64 buckets
      int t = threadIdx.x;
      int v = hist[t];
      int incl = v;
#pragma unroll
      for (int ofs = 1; ofs < 64; ofs <<= 1) {
        int w = __shfl_up(incl, ofs);
        if (t >= ofs) incl += w;
      }
      excl[t] = incl - v;
      lcur[t] = incl - v;
    }
    __syncthreads();
#pragma unroll
    for (int k = 0; k < 16; ++k) {
      int li = threadIdx.x + k * 256;
      if (li < cnt) {
        int c = myD[k] >> CSHIFT;
        int p = atomicAdd(&lcur[c], 1);
        stage[p] = (unsigned int)myS[k] | ((unsigned int)(myD[k] & CMASK) << 17);
        bid[p] = (unsigned char)c;
      }
    }
    __syncthreads();
    if (threadIdx.x < NCMAX) {
      int t = threadIdx.x;
      int cc = lcur[t] - excl[t];
      gbase[t] = cc ? atomicAdd(&ccur[t * 16], cc) : 0;
    }
    __syncthreads();
    for (int i = threadIdx.x; i < cnt; i += 256) {
      int c = bid[i];
      packed[gbase[c] + (i - excl[c])] = stage[i];
    }
    __syncthreads();  // protect hist/stage reuse
  }
}

// one block per coarse bucket: counting sort 2048 node sub-buckets -> csr, off, dinv.
__global__ __launch_bounds__(512) void csr_fine_kernel(const unsigned int* __restrict__ packed,
    const int* __restrict__ coff, int* __restrict__ off, float* __restrict__ dinv,
    int* __restrict__ csr, int n) {
  __shared__ int lh[2048];
  __shared__ int lsum[512];
  int b = blockIdx.x;
  int t = threadIdx.x;
  int e0 = coff[b], e1 = coff[b + 1];
  int node0 = b << CSHIFT;
  for (int i = t; i < 2048; i += 512) lh[i] = 0;
  __syncthreads();
  for (int i = e0 + t; i < e1; i += 512) atomicAdd(&lh[packed[i] >> 17], 1);
  __syncthreads();
  int base = t * 4;
  int v0 = lh[base], v1 = lh[base + 1], v2 = lh[base + 2], v3 = lh[base + 3];
  int tsum = v0 + v1 + v2 + v3;
  lsum[t] = tsum;
  __syncthreads();
  for (int ofs = 1; ofs < 512; ofs <<= 1) {
    int add = (t >= ofs) ? lsum[t - ofs] : 0;
    __syncthreads();
    lsum[t] += add;
    __syncthreads();
  }
  int ex = lsum[t] - tsum;
  int exc0 = ex, exc1 = ex + v0, exc2 = ex + v0 + v1, exc3 = ex + v0 + v1 + v2;
  lh[base] = exc0; lh[base + 1] = exc1; lh[base + 2] = exc2; lh[base + 3] = exc3;
  int node = node0 + base;
  if (node < n)     { off[node]     = e0 + exc0; dinv[node]     = rsqrtf((float)(v0 + 1)); }
  if (node + 1 < n) { off[node + 1] = e0 + exc1; dinv[node + 1] = rsqrtf((float)(v1 + 1)); }
  if (node + 2 < n) { off[node + 2] = e0 + exc2; dinv[node + 2] = rsqrtf((float)(v2 + 1)); }
  if (node + 3 < n) { off[node + 3] = e0 + exc3; dinv[node + 3] = rsqrtf((float)(v3 + 1)); }
  __syncthreads();
  for (int i = e0 + t; i < e1; i += 512) {
    unsigned int p = packed[i];
    int nl = p >> 17;
    int pos = atomicAdd(&lh[nl], 1);
    csr[e0 + pos] = (int)(p & 0x1FFFFu);
  }
}

// ---------- h1' = dinv * (x @ W1) via MFMA, output bf16 ----------
__global__ __launch_bounds__(256) void gemm1_kernel(const float* __restrict__ x,
    const float* __restrict__ W1, const float* __restrict__ dinv,
    unsigned int* __restrict__ h1, int n) {
  __shared__ unsigned int xs[64 * 64];  // 16 KB
  __shared__ unsigned int wt[64 * 64];  // 16 KB
  // W1[k][c] -> wt[c][k-pairs], bf16-packed, swizzled
  for (int i = threadIdx.x; i < 4096; i += 256) {
    int c = i & 63, kp = i >> 6;             // kp = k-pair index 0..63
    float a = W1[(2 * kp) * 64 + c];
    float b = W1[(2 * kp + 1) * 64 + c];
    int slot = kp >> 2;                      // 16B slot (4 uints)
    int slotS = slot ^ (c & 7);
    wt[c * 64 + slotS * 4 + (kp & 3)] = pack_bf16(a, b);
  }
  int row0 = blockIdx.x * 64;
  int nrow = n - row0; if (nrow > 64) nrow = 64;
  // x tile -> bf16, swizzled
  for (int i = threadIdx.x; i < 64 * 32; i += 256) {
    int r = i >> 5, q = i & 31;              // q = float4 quad (k = 4q..4q+3)
    float4 v = make_float4(0.f, 0.f, 0.f, 0.f);
    if (r < nrow) v = ((const float4*)(x + (size_t)(row0 + r) * 128))[q];
    int slot = q >> 1;
    int slotS = slot ^ (r & 7);
    int bi = r * 64 + slotS * 4 + (q & 1) * 2;
    xs[bi]     = pack_bf16(v.x, v.y);
    xs[bi + 1] = pack_bf16(v.z, v.w);
  }
  __syncthreads();
  int lane = threadIdx.x & 63;
  int w = threadIdx.x >> 6;
  int rl = lane & 15;
  int g = lane >> 4;
  f32x4 acc[4];
#pragma unroll
  for (int i = 0; i < 4; ++i) acc[i] = (f32x4){0.f, 0.f, 0.f, 0.f};
#pragma unroll
  for (int ks = 0; ks < 4; ++ks) {
    int as = ((ks * 4 + g) ^ (rl & 7)) * 4;
    bf16x8 af = *reinterpret_cast<const bf16x8*>(&xs[(w * 16 + rl) * 64 + as]);
#pragma unroll
    for (int nt = 0; nt < 4; ++nt) {
      int col = nt * 16 + rl;
      int bs = ((ks * 4 + g) ^ (col & 7)) * 4;
      bf16x8 bfr = *reinterpret_cast<const bf16x8*>(&wt[col * 64 + bs]);
      acc[nt] = __builtin_amdgcn_mfma_f32_16x16x32_bf16(af, bfr, acc[nt], 0, 0, 0);
    }
  }
  // epilogue: reg i -> row_local = g*4+i, col = nt*16+rl; scale by dinv, pack pairs
#pragma unroll
  for (int i = 0; i < 4; ++i) {
    int row = row0 + w * 16 + g * 4 + i;
    float dv = (row < n) ? dinv[row] : 0.f;
#pragma unroll
    for (int nt = 0; nt < 4; ++nt) {
      float val = dv * acc[nt][i];
      float pv = __shfl_xor(val, 1);
      if (!(lane & 1) && row < n) {
        h1[(size_t)row * 32 + nt * 8 + (rl >> 1)] = pack_bf16(val, pv);
      }
    }
  }
}

// ---------- aggregation ----------
// 2 nodes x 16 edge-slots x 2 feature-lanes per wave. h rows dinv-prefolded.
// FP8IN=0: rows are 128B bf16 (8 uint4); FP8IN=1: rows are 64B fp8 e4m3 (4 uint4).
// acc = h'[node] + sum_{e:dst=node} h'[src];  result = dinv[node]*acc.
// Static recursive-halving reduce; every lane ends with 2 features.
// EPI=1: out = fp8( dinv * tanh(result + bias) )  (layer-2 table, 64B rows)
// EPI=0: out = bf16( result )                     (final agg, 128B rows)
template <int EPI, int FP8IN>
__global__ __launch_bounds__(256) void agg_kernel(const uint4* __restrict__ h4,
    const int* __restrict__ off, const int* __restrict__ csr,
    const float* __restrict__ dinv, const float* __restrict__ bias,
    unsigned int* __restrict__ out, int n) {
  int lane = threadIdx.x & 63;
  int nd = lane >> 5;            // which of the wave's 2 nodes
  int j  = (lane >> 1) & 15;     // edge slot 0..15
  int fl = lane & 1;             // feature half (32 features per lane)
  int node = blockIdx.x * 8 + (threadIdx.x >> 6) * 2 + nd;
  bool valid = node < n;
  float acc[32];
#pragma unroll
  for (int i = 0; i < 32; ++i) acc[i] = 0.f;
  if (valid) {
    if (j == 0) {  // self loop
      if (FP8IN) {
        const uint4* hp = &h4[(size_t)node * 4 + fl * 2];
        uint4 a = hp[0], b = hp[1];
        add16_fp8(acc, a); add16_fp8(acc + 16, b);
      } else {
        const uint4* hp = &h4[(size_t)node * 8 + fl * 4];
        uint4 a = hp[0], b = hp[1], c = hp[2], d = hp[3];
        add8(acc, a); add8(acc + 8, b); add8(acc + 16, c); add8(acc + 24, d);
      }
    }
    int e1 = off[node + 1];
    for (int ee = off[node] + j; ee < e1; ee += 16) {
      int s = __builtin_nontemporal_load(&csr[ee]);
      if (FP8IN) {
        const uint4* hp = &h4[(size_t)s * 4 + fl * 2];
        uint4 a = hp[0], b = hp[1];
        add16_fp8(acc, a); add16_fp8(acc + 16, b);
      } else {
        const uint4* hp = &h4[(size_t)s * 8 + fl * 4];
        uint4 a = hp[0], b = hp[1], c = hp[2], d = hp[3];
        add8(acc, a); add8(acc + 8, b); add8(acc + 16, c); add8(acc + 24, d);
      }
    }
  }
  // reduce over slot bits (lane bits 1..4); features 32 -> 2 per lane
#pragma unroll
  for (int i = 0; i < 16; ++i) {
    float tlo = acc[i]      + __shfl_xor(acc[i], 2);
    float thi = acc[i + 16] + __shfl_xor(acc[i + 16], 2);
    acc[i] = (j & 1) ? thi : tlo;
  }
#pragma unroll
  for (int i = 0; i < 8; ++i) {
    float tlo = acc[i]     + __shfl_xor(acc[i], 4);
    float thi = acc[i + 8] + __shfl_xor(acc[i + 8], 4);
    acc[i] = (j & 2) ? thi : tlo;
  }
#pragma unroll
  for (int i = 0; i < 4; ++i) {
    float tlo = acc[i]     + __shfl_xor(acc[i], 8);
    float thi = acc[i + 4] + __shfl_xor(acc[i + 4], 8);
    acc[i] = (j & 4) ? thi : tlo;
  }
#pragma unroll
  for (int i = 0; i < 2; ++i) {
    float tlo = acc[i]     + __shfl_xor(acc[i], 16);
    float thi = acc[i + 2] + __shfl_xor(acc[i + 2], 16);
    acc[i] = (j & 8) ? thi : tlo;
  }
  // lane owns features f0, f0+1 with f0 = fl*32 + 16*b0 + 8*b1 + 4*b2 + 2*b3
  int b0 = j & 1, b1 = (j >> 1) & 1, b2 = (j >> 2) & 1, b3 = (j >> 3) & 1;
  int f0 = fl * 32 + 16 * b0 + 8 * b1 + 4 * b2 + 2 * b3;
  if (valid) {
    float di = dinv[node];
    if (EPI) {
      float v0 = di * tanhf(fmaf(di, acc[0], bias[f0]));
      float v1 = di * tanhf(fmaf(di, acc[1], bias[f0 + 1]));
      unsigned int pk = __builtin_amdgcn_cvt_pk_fp8_f32(v0, v1, 0u, false);
      ((unsigned short*)out)[(size_t)node * 32 + (f0 >> 1)] = (unsigned short)pk;
    } else {
      float v0 = di * acc[0];
      float v1 = di * acc[1];
      out[(size_t)node * 32 + (f0 >> 1)] = pack_bf16(v0, v1);
    }
  }
}

// ---------- final: mean/logvar GEMMs + reparam ----------
__global__ __launch_bounds__(256) void final_kernel(const unsigned int* __restrict__ aggb,
    const float* __restrict__ Wm, const float* __restrict__ bm,
    const float* __restrict__ Wv, const float* __restrict__ bv,
    const float* __restrict__ noise, float* __restrict__ outZ,
    float* __restrict__ outM, float* __restrict__ outLv, int n) {
  __shared__ float WmS[64 * 32];
  __shared__ float WvS[64 * 32];
  __shared__ float aggS[64 * 68];  // stride 68 breaks bank conflicts
  for (int i = threadIdx.x; i < 64 * 8; i += 256) {
    ((float4*)WmS)[i] = ((const float4*)Wm)[i];
    ((float4*)WvS)[i] = ((const float4*)Wv)[i];
  }
  int row0 = blockIdx.x * 64;
  int nrow = n - row0; if (nrow > 64) nrow = 64;
  for (int i = threadIdx.x; i < 64 * 16; i += 256) {
    int r = i >> 4, g = i & 15;
    uint2 u = make_uint2(0u, 0u);
    if (r < nrow) u = ((const uint2*)aggb)[(size_t)(row0 + r) * 16 + g];
    float* d = &aggS[r * 68 + g * 4];
    d[0] = __uint_as_float(u.x << 16);
    d[1] = __uint_as_float(u.x & 0xFFFF0000u);
    d[2] = __uint_as_float(u.y << 16);
    d[3] = __uint_as_float(u.y & 0xFFFF0000u);
  }
  __syncthreads();
  int c4 = (threadIdx.x & 7) * 4;
  int r2 = (threadIdx.x >> 3) * 2;
  float4 am[2], av[2];
#pragma unroll
  for (int i = 0; i < 2; ++i) {
    am[i] = make_float4(0.f, 0.f, 0.f, 0.f);
    av[i] = make_float4(0.f, 0.f, 0.f, 0.f);
  }
#pragma unroll 4
  for (int kq = 0; kq < 16; ++kq) {
    float4 xa[2], wm[4], wv[4];
#pragma unroll
    for (int i = 0; i < 2; ++i) xa[i] = *(const float4*)&aggS[(r2 + i) * 68 + kq * 4];
#pragma unroll
    for (int q = 0; q < 4; ++q) {
      wm[q] = *(const float4*)&WmS[(kq * 4 + q) * 32 + c4];
      wv[q] = *(const float4*)&WvS[(kq * 4 + q) * 32 + c4];
    }
#pragma unroll
    for (int i = 0; i < 2; ++i) {
      fma4(am[i], xa[i].x, wm[0]); fma4(am[i], xa[i].y, wm[1]);
      fma4(am[i], xa[i].z, wm[2]); fma4(am[i], xa[i].w, wm[3]);
      fma4(av[i], xa[i].x, wv[0]); fma4(av[i], xa[i].y, wv[1]);
      fma4(av[i], xa[i].z, wv[2]); fma4(av[i], xa[i].w, wv[3]);
    }
  }
  float4 bmv = *(const float4*)&bm[c4];
  float4 bvv = *(const float4*)&bv[c4];
#pragma unroll
  for (int i = 0; i < 2; ++i) {
    int row = row0 + r2 + i;
    if (row < n) {
      float4 m = am[i]; m.x += bmv.x; m.y += bmv.y; m.z += bmv.z; m.w += bmv.w;
      float4 v = av[i]; v.x += bvv.x; v.y += bvv.y; v.z += bvv.z; v.w += bvv.w;
      size_t oi = (size_t)row * 8 + (threadIdx.x & 7);
      float4 nz = ((const float4*)noise)[oi];
      float4 z;
      z.x = fmaf(nz.x, expf(0.5f * v.x), m.x);
      z.y = fmaf(nz.y, expf(0.5f * v.y), m.y);
      z.z = fmaf(nz.z, expf(0.5f * v.z), m.z);
      z.w = fmaf(nz.w, expf(0.5f * v.w), m.w);
      ((float4*)outZ)[oi] = z;
      ((float4*)outM)[oi] = m;
      ((float4*)outLv)[oi] = v;
    }
  }
}

// ---------- launch ----------

extern "C" void kernel_launch(void* const* d_in, const int* in_sizes, int n_in,
                              void* d_out, int out_size, void* d_ws, size_t ws_size,
                              hipStream_t stream) {
  const float* x     = (const float*)d_in[0];
  const int*   edge  = (const int*)d_in[1];
  const float* W1    = (const float*)d_in[2];
  const float* b1    = (const float*)d_in[3];
  const float* Wm    = (const float*)d_in[4];
  const float* bm    = (const float*)d_in[5];
  const float* Wv    = (const float*)d_in[6];
  const float* bv    = (const float*)d_in[7];
  const float* noise = (const float*)d_in[8];
  int n = in_sizes[0] / 128;
  int e = in_sizes[1] / 2;
  const int* src = edge;
  const int* dst = edge + e;
  int nc = (n + CMASK) >> CSHIFT;   // 49 coarse buckets of 2048 nodes

  // workspace layout (int units, 16B-aligned segments)
  int* ccnt = (int*)d_ws;                          // NCMAX*16 (1 per 64B line)
  int* ccur = ccnt + NCMAX * 16;                   // NCMAX*16
  int* coff = ccur + NCMAX * 16;                   // NCMAX+1 (+pad)
  int* off  = coff + (NCMAX + 4);                  // n+1 (+pad)
  float* dinv = (float*)(off + ((n + 4) & ~3));    // n
  unsigned int* packed = (unsigned int*)(dinv + ((n + 3) & ~3)); // e
  int* csr  = (int*)(packed + ((e + 3) & ~3));     // e
  unsigned int* h1b = (unsigned int*)(csr + ((e + 3) & ~3)); // n*32 (bf16 h1')
  unsigned int* hb  = h1b + (size_t)n * 32;                  // n*16 (fp8 h')
  unsigned int* aggb = hb + (size_t)n * 16;                  // n*32 (bf16 agg2)

  float* outZ  = (float*)d_out;
  float* outM  = outZ + (size_t)n * 32;
  float* outLv = outM + (size_t)n * 32;

  int ntiles = (e + TILE - 1) / TILE;

  zero_kernel<<<(NCMAX * 16 + 255) / 256, 256, 0, stream>>>(ccnt, NCMAX * 16);
  coarse_hist_kernel<<<512, 256, 0, stream>>>(dst, ccnt, e);
  coarse_scan_kernel<<<1, 64, 0, stream>>>(ccnt, coff, ccur, off, nc, n, e);
  coarse_partition_kernel<<<ntiles, 256, 0, stream>>>(src, dst, ccur, packed, e);
  csr_fine_kernel<<<nc, 512, 0, stream>>>(packed, coff, off, dinv, csr, n);
  gemm1_kernel<<<(n + 63) / 64, 256, 0, stream>>>(x, W1, dinv, h1b, n);
  agg_kernel<1, 0><<<(n + 7) / 8, 256, 0, stream>>>((const uint4*)h1b, off, csr, dinv, b1, hb, n);
  agg_kernel<0, 1><<<(n + 7) / 8, 256, 0, stream>>>((const uint4*)hb, off, csr, dinv, b1, aggb, n);
  final_kernel<<<(n + 63) / 64, 256, 0, stream>>>(aggb, Wm, bm, Wv, bv, noise, outZ, outM, outLv, n);
}

// Round 13
// 184.555 us; speedup vs baseline: 1.5602x; 1.0329x over previous
//
#include <hip/hip_runtime.h>
#include <math.h>

#define TILE 4096          // edges per partition tile
#define CSHIFT 11          // coarse bucket = dst >> 11  (2048 nodes)
#define CMASK 2047
#define NCMAX 64

typedef __attribute__((ext_vector_type(8))) short bf16x8;   // 8 bf16 (4 VGPRs)
typedef __attribute__((ext_vector_type(4))) float f32x4;
typedef __attribute__((ext_vector_type(2))) float f32x2;

// ---------- helpers ----------

__device__ __forceinline__ unsigned int pack_bf16(float a, float b) {
  unsigned int ua = __float_as_uint(a);
  ua += 0x7FFFu + ((ua >> 16) & 1u);
  unsigned int ub = __float_as_uint(b);
  ub += 0x7FFFu + ((ub >> 16) & 1u);
  return (ua >> 16) | (ub & 0xFFFF0000u);
}

// acc[0..15] += fp8x16(hv)  (e4m3, HW decode)
__device__ __forceinline__ void add16_fp8(float* acc, uint4 hv) {
  unsigned int u[4] = {hv.x, hv.y, hv.z, hv.w};
#pragma unroll
  for (int i = 0; i < 4; ++i) {
    f32x2 lo = __builtin_amdgcn_cvt_pk_f32_fp8(u[i], false);
    f32x2 hi = __builtin_amdgcn_cvt_pk_f32_fp8(u[i], true);
    acc[4 * i + 0] += lo[0];
    acc[4 * i + 1] += lo[1];
    acc[4 * i + 2] += hi[0];
    acc[4 * i + 3] += hi[1];
  }
}

__device__ __forceinline__ void fma4(float4& acc, float s, const float4& w) {
  acc.x = fmaf(s, w.x, acc.x);
  acc.y = fmaf(s, w.y, acc.y);
  acc.z = fmaf(s, w.z, acc.z);
  acc.w = fmaf(s, w.w, acc.w);
}

// ---------- CSR build: two-level LDS-staged split ----------

// 4 LDS replicas per bucket to cut same-address atomic serialization
__global__ __launch_bounds__(256) void coarse_hist_kernel(const int* __restrict__ dst,
    int* __restrict__ ccnt, int e) {
  __shared__ int h[NCMAX * 4];
  for (int i = threadIdx.x; i < NCMAX * 4; i += 256) h[i] = 0;
  __syncthreads();
  int rep = threadIdx.x & 3;
  for (int i = blockIdx.x * 256 + threadIdx.x; i < e; i += gridDim.x * 256)
    atomicAdd(&h[((dst[i] >> CSHIFT) << 2) | rep], 1);
  __syncthreads();
  for (int i = threadIdx.x; i < NCMAX; i += 256) {
    int s = h[i * 4] + h[i * 4 + 1] + h[i * 4 + 2] + h[i * 4 + 3];
    if (s) atomicAdd(&ccnt[i * 16], s);
  }
}

// single wave: exclusive scan of nc coarse counts; init cursors; off[n]=e
__global__ __launch_bounds__(64) void coarse_scan_kernel(const int* __restrict__ ccnt,
    int* __restrict__ coff, int* __restrict__ ccur, int* __restrict__ off,
    int nc, int n, int e) {
  int t = threadIdx.x;
  int v = (t < nc) ? ccnt[t * 16] : 0;
  int incl = v;
#pragma unroll
  for (int ofs = 1; ofs < 64; ofs <<= 1) {
    int w = __shfl_up(incl, ofs);
    if (t >= ofs) incl += w;
  }
  int excl = incl - v;
  if (t < nc) { coff[t] = excl; ccur[t * 16] = excl; }
  if (t == nc - 1) coff[nc] = incl;
  if (t == 0) off[n] = e;
}

// LDS-staged partition: sort a 4096-edge tile by coarse bucket in LDS, reserve
// a global range per bucket with ONE atomic, stream out contiguous segments.
__global__ __launch_bounds__(256) void coarse_partition_kernel(const int* __restrict__ src,
    const int* __restrict__ dst, int* __restrict__ ccur,
    unsigned int* __restrict__ packed, int e) {
  __shared__ unsigned int stage[TILE];
  __shared__ unsigned char bid[TILE];
  __shared__ int hist[NCMAX], excl[NCMAX], gbase[NCMAX], lcur[NCMAX];
  int ntiles = (e + TILE - 1) / TILE;
  for (int tile = blockIdx.x; tile < ntiles; tile += gridDim.x) {
    int i0 = tile * TILE;
    int cnt = e - i0; if (cnt > TILE) cnt = TILE;
    if (threadIdx.x < NCMAX) hist[threadIdx.x] = 0;
    __syncthreads();
    int myS[16], myD[16];
#pragma unroll
    for (int k = 0; k < 16; ++k) {
      int li = threadIdx.x + k * 256;
      if (li < cnt) {
        myS[k] = src[i0 + li];
        myD[k] = dst[i0 + li];
        atomicAdd(&hist[myD[k] >> CSHIFT], 1);
      }
    }
    __syncthreads();
    if (threadIdx.x < NCMAX) {  // wave 0: scan 64 buckets
      int t = threadIdx.x;
      int v = hist[t];
      int incl = v;
#pragma unroll
      for (int ofs = 1; ofs < 64; ofs <<= 1) {
        int w = __shfl_up(incl, ofs);
        if (t >= ofs) incl += w;
      }
      excl[t] = incl - v;
      lcur[t] = incl - v;
    }
    __syncthreads();
#pragma unroll
    for (int k = 0; k < 16; ++k) {
      int li = threadIdx.x + k * 256;
      if (li < cnt) {
        int c = myD[k] >> CSHIFT;
        int p = atomicAdd(&lcur[c], 1);
        stage[p] = (unsigned int)myS[k] | ((unsigned int)(myD[k] & CMASK) << 17);
        bid[p] = (unsigned char)c;
      }
    }
    __syncthreads();
    if (threadIdx.x < NCMAX) {
      int t = threadIdx.x;
      int cc = lcur[t] - excl[t];
      gbase[t] = cc ? atomicAdd(&ccur[t * 16], cc) : 0;
    }
    __syncthreads();
    for (int i = threadIdx.x; i < cnt; i += 256) {
      int c = bid[i];
      packed[gbase[c] + (i - excl[c])] = stage[i];
    }
    __syncthreads();  // protect hist/stage reuse
  }
}

// one block per coarse bucket: counting sort 2048 node sub-buckets -> csr, off, dinv.
__global__ __launch_bounds__(512) void csr_fine_kernel(const unsigned int* __restrict__ packed,
    const int* __restrict__ coff, int* __restrict__ off, float* __restrict__ dinv,
    int* __restrict__ csr, int n) {
  __shared__ int lh[2048];
  __shared__ int lsum[512];
  int b = blockIdx.x;
  int t = threadIdx.x;
  int e0 = coff[b], e1 = coff[b + 1];
  int node0 = b << CSHIFT;
  for (int i = t; i < 2048; i += 512) lh[i] = 0;
  __syncthreads();
  for (int i = e0 + t; i < e1; i += 512) atomicAdd(&lh[packed[i] >> 17], 1);
  __syncthreads();
  int base = t * 4;
  int v0 = lh[base], v1 = lh[base + 1], v2 = lh[base + 2], v3 = lh[base + 3];
  int tsum = v0 + v1 + v2 + v3;
  lsum[t] = tsum;
  __syncthreads();
  for (int ofs = 1; ofs < 512; ofs <<= 1) {
    int add = (t >= ofs) ? lsum[t - ofs] : 0;
    __syncthreads();
    lsum[t] += add;
    __syncthreads();
  }
  int ex = lsum[t] - tsum;
  int exc0 = ex, exc1 = ex + v0, exc2 = ex + v0 + v1, exc3 = ex + v0 + v1 + v2;
  lh[base] = exc0; lh[base + 1] = exc1; lh[base + 2] = exc2; lh[base + 3] = exc3;
  int node = node0 + base;
  if (node < n)     { off[node]     = e0 + exc0; dinv[node]     = rsqrtf((float)(v0 + 1)); }
  if (node + 1 < n) { off[node + 1] = e0 + exc1; dinv[node + 1] = rsqrtf((float)(v1 + 1)); }
  if (node + 2 < n) { off[node + 2] = e0 + exc2; dinv[node + 2] = rsqrtf((float)(v2 + 1)); }
  if (node + 3 < n) { off[node + 3] = e0 + exc3; dinv[node + 3] = rsqrtf((float)(v3 + 1)); }
  __syncthreads();
  for (int i = e0 + t; i < e1; i += 512) {
    unsigned int p = packed[i];
    int nl = p >> 17;
    int pos = atomicAdd(&lh[nl], 1);
    csr[e0 + pos] = (int)(p & 0x1FFFFu);
  }
}

// ---------- h1' = dinv * (x @ W1) via MFMA, output fp8 e4m3 ----------
__global__ __launch_bounds__(256) void gemm1_kernel(const float* __restrict__ x,
    const float* __restrict__ W1, const float* __restrict__ dinv,
    unsigned int* __restrict__ h1, int n) {
  __shared__ unsigned int xs[64 * 64];  // 16 KB
  __shared__ unsigned int wt[64 * 64];  // 16 KB
  // W1[k][c] -> wt[c][k-pairs], bf16-packed, swizzled
  for (int i = threadIdx.x; i < 4096; i += 256) {
    int c = i & 63, kp = i >> 6;             // kp = k-pair index 0..63
    float a = W1[(2 * kp) * 64 + c];
    float b = W1[(2 * kp + 1) * 64 + c];
    int slot = kp >> 2;                      // 16B slot (4 uints)
    int slotS = slot ^ (c & 7);
    wt[c * 64 + slotS * 4 + (kp & 3)] = pack_bf16(a, b);
  }
  int row0 = blockIdx.x * 64;
  int nrow = n - row0; if (nrow > 64) nrow = 64;
  // x tile -> bf16, swizzled
  for (int i = threadIdx.x; i < 64 * 32; i += 256) {
    int r = i >> 5, q = i & 31;              // q = float4 quad (k = 4q..4q+3)
    float4 v = make_float4(0.f, 0.f, 0.f, 0.f);
    if (r < nrow) v = ((const float4*)(x + (size_t)(row0 + r) * 128))[q];
    int slot = q >> 1;
    int slotS = slot ^ (r & 7);
    int bi = r * 64 + slotS * 4 + (q & 1) * 2;
    xs[bi]     = pack_bf16(v.x, v.y);
    xs[bi + 1] = pack_bf16(v.z, v.w);
  }
  __syncthreads();
  int lane = threadIdx.x & 63;
  int w = threadIdx.x >> 6;
  int rl = lane & 15;
  int g = lane >> 4;
  f32x4 acc[4];
#pragma unroll
  for (int i = 0; i < 4; ++i) acc[i] = (f32x4){0.f, 0.f, 0.f, 0.f};
#pragma unroll
  for (int ks = 0; ks < 4; ++ks) {
    int as = ((ks * 4 + g) ^ (rl & 7)) * 4;
    bf16x8 af = *reinterpret_cast<const bf16x8*>(&xs[(w * 16 + rl) * 64 + as]);
#pragma unroll
    for (int nt = 0; nt < 4; ++nt) {
      int col = nt * 16 + rl;
      int bs = ((ks * 4 + g) ^ (col & 7)) * 4;
      bf16x8 bfr = *reinterpret_cast<const bf16x8*>(&wt[col * 64 + bs]);
      acc[nt] = __builtin_amdgcn_mfma_f32_16x16x32_bf16(af, bfr, acc[nt], 0, 0, 0);
    }
  }
  // epilogue: reg i -> row_local = g*4+i, col = nt*16+rl; scale by dinv, fp8 pairs
#pragma unroll
  for (int i = 0; i < 4; ++i) {
    int row = row0 + w * 16 + g * 4 + i;
    float dv = (row < n) ? dinv[row] : 0.f;
#pragma unroll
    for (int nt = 0; nt < 4; ++nt) {
      float val = dv * acc[nt][i];
      float pv = __shfl_xor(val, 1);
      if (!(lane & 1) && row < n) {
        unsigned int pk = __builtin_amdgcn_cvt_pk_fp8_f32(val, pv, 0u, false);
        ((unsigned short*)h1)[(size_t)row * 32 + nt * 8 + (rl >> 1)] = (unsigned short)pk;
      }
    }
  }
}

// ---------- aggregation ----------
// 2 nodes x 16 edge-slots x 2 feature-lanes per wave. Rows: 64B fp8 e4m3.
// acc = h'[node] + sum_{e:dst=node} h'[src];  result = dinv[node]*acc.
// Static recursive-halving reduce; every lane ends with 2 features.
// EPI=1: out = fp8( dinv * tanh(result + bias) )  (layer-2 table, 64B rows)
// EPI=0: out = bf16( result )                     (final agg, 128B rows)
template <int EPI>
__global__ __launch_bounds__(256) void agg_kernel(const uint4* __restrict__ h4,
    const int* __restrict__ off, const int* __restrict__ csr,
    const float* __restrict__ dinv, const float* __restrict__ bias,
    unsigned int* __restrict__ out, int n) {
  int lane = threadIdx.x & 63;
  int nd = lane >> 5;            // which of the wave's 2 nodes
  int j  = (lane >> 1) & 15;     // edge slot 0..15
  int fl = lane & 1;             // feature half (32 features per lane)
  int node = blockIdx.x * 8 + (threadIdx.x >> 6) * 2 + nd;
  bool valid = node < n;
  float acc[32];
#pragma unroll
  for (int i = 0; i < 32; ++i) acc[i] = 0.f;
  if (valid) {
    if (j == 0) {  // self loop
      const uint4* hp = &h4[(size_t)node * 4 + fl * 2];
      uint4 a = hp[0], b = hp[1];
      add16_fp8(acc, a); add16_fp8(acc + 16, b);
    }
    int e1 = off[node + 1];
    for (int ee = off[node] + j; ee < e1; ee += 16) {
      int s = __builtin_nontemporal_load(&csr[ee]);
      const uint4* hp = &h4[(size_t)s * 4 + fl * 2];
      uint4 a = hp[0], b = hp[1];
      add16_fp8(acc, a); add16_fp8(acc + 16, b);
    }
  }
  // reduce over slot bits (lane bits 1..4); features 32 -> 2 per lane
#pragma unroll
  for (int i = 0; i < 16; ++i) {
    float tlo = acc[i]      + __shfl_xor(acc[i], 2);
    float thi = acc[i + 16] + __shfl_xor(acc[i + 16], 2);
    acc[i] = (j & 1) ? thi : tlo;
  }
#pragma unroll
  for (int i = 0; i < 8; ++i) {
    float tlo = acc[i]     + __shfl_xor(acc[i], 4);
    float thi = acc[i + 8] + __shfl_xor(acc[i + 8], 4);
    acc[i] = (j & 2) ? thi : tlo;
  }
#pragma unroll
  for (int i = 0; i < 4; ++i) {
    float tlo = acc[i]     + __shfl_xor(acc[i], 8);
    float thi = acc[i + 4] + __shfl_xor(acc[i + 4], 8);
    acc[i] = (j & 4) ? thi : tlo;
  }
#pragma unroll
  for (int i = 0; i < 2; ++i) {
    float tlo = acc[i]     + __shfl_xor(acc[i], 16);
    float thi = acc[i + 2] + __shfl_xor(acc[i + 2], 16);
    acc[i] = (j & 8) ? thi : tlo;
  }
  // lane owns features f0, f0+1 with f0 = fl*32 + 16*b0 + 8*b1 + 4*b2 + 2*b3
  int b0 = j & 1, b1 = (j >> 1) & 1, b2 = (j >> 2) & 1, b3 = (j >> 3) & 1;
  int f0 = fl * 32 + 16 * b0 + 8 * b1 + 4 * b2 + 2 * b3;
  if (valid) {
    float di = dinv[node];
    if (EPI) {
      float v0 = di * tanhf(fmaf(di, acc[0], bias[f0]));
      float v1 = di * tanhf(fmaf(di, acc[1], bias[f0 + 1]));
      unsigned int pk = __builtin_amdgcn_cvt_pk_fp8_f32(v0, v1, 0u, false);
      ((unsigned short*)out)[(size_t)node * 32 + (f0 >> 1)] = (unsigned short)pk;
    } else {
      float v0 = di * acc[0];
      float v1 = di * acc[1];
      out[(size_t)node * 32 + (f0 >> 1)] = pack_bf16(v0, v1);
    }
  }
}

// ---------- final: mean/logvar GEMMs + reparam ----------
__global__ __launch_bounds__(256) void final_kernel(const unsigned int* __restrict__ aggb,
    const float* __restrict__ Wm, const float* __restrict__ bm,
    const float* __restrict__ Wv, const float* __restrict__ bv,
    const float* __restrict__ noise, float* __restrict__ outZ,
    float* __restrict__ outM, float* __restrict__ outLv, int n) {
  __shared__ float WmS[64 * 32];
  __shared__ float WvS[64 * 32];
  __shared__ float aggS[64 * 68];  // stride 68 breaks bank conflicts
  for (int i = threadIdx.x; i < 64 * 8; i += 256) {
    ((float4*)WmS)[i] = ((const float4*)Wm)[i];
    ((float4*)WvS)[i] = ((const float4*)Wv)[i];
  }
  int row0 = blockIdx.x * 64;
  int nrow = n - row0; if (nrow > 64) nrow = 64;
  for (int i = threadIdx.x; i < 64 * 16; i += 256) {
    int r = i >> 4, g = i & 15;
    uint2 u = make_uint2(0u, 0u);
    if (r < nrow) u = ((const uint2*)aggb)[(size_t)(row0 + r) * 16 + g];
    float* d = &aggS[r * 68 + g * 4];
    d[0] = __uint_as_float(u.x << 16);
    d[1] = __uint_as_float(u.x & 0xFFFF0000u);
    d[2] = __uint_as_float(u.y << 16);
    d[3] = __uint_as_float(u.y & 0xFFFF0000u);
  }
  __syncthreads();
  int c4 = (threadIdx.x & 7) * 4;
  int r2 = (threadIdx.x >> 3) * 2;
  float4 am[2], av[2];
#pragma unroll
  for (int i = 0; i < 2; ++i) {
    am[i] = make_float4(0.f, 0.f, 0.f, 0.f);
    av[i] = make_float4(0.f, 0.f, 0.f, 0.f);
  }
#pragma unroll 4
  for (int kq = 0; kq < 16; ++kq) {
    float4 xa[2], wm[4], wv[4];
#pragma unroll
    for (int i = 0; i < 2; ++i) xa[i] = *(const float4*)&aggS[(r2 + i) * 68 + kq * 4];
#pragma unroll
    for (int q = 0; q < 4; ++q) {
      wm[q] = *(const float4*)&WmS[(kq * 4 + q) * 32 + c4];
      wv[q] = *(const float4*)&WvS[(kq * 4 + q) * 32 + c4];
    }
#pragma unroll
    for (int i = 0; i < 2; ++i) {
      fma4(am[i], xa[i].x, wm[0]); fma4(am[i], xa[i].y, wm[1]);
      fma4(am[i], xa[i].z, wm[2]); fma4(am[i], xa[i].w, wm[3]);
      fma4(av[i], xa[i].x, wv[0]); fma4(av[i], xa[i].y, wv[1]);
      fma4(av[i], xa[i].z, wv[2]); fma4(av[i], xa[i].w, wv[3]);
    }
  }
  float4 bmv = *(const float4*)&bm[c4];
  float4 bvv = *(const float4*)&bv[c4];
#pragma unroll
  for (int i = 0; i < 2; ++i) {
    int row = row0 + r2 + i;
    if (row < n) {
      float4 m = am[i]; m.x += bmv.x; m.y += bmv.y; m.z += bmv.z; m.w += bmv.w;
      float4 v = av[i]; v.x += bvv.x; v.y += bvv.y; v.z += bvv.z; v.w += bvv.w;
      size_t oi = (size_t)row * 8 + (threadIdx.x & 7);
      float4 nz = ((const float4*)noise)[oi];
      float4 z;
      z.x = fmaf(nz.x, expf(0.5f * v.x), m.x);
      z.y = fmaf(nz.y, expf(0.5f * v.y), m.y);
      z.z = fmaf(nz.z, expf(0.5f * v.z), m.z);
      z.w = fmaf(nz.w, expf(0.5f * v.w), m.w);
      ((float4*)outZ)[oi] = z;
      ((float4*)outM)[oi] = m;
      ((float4*)outLv)[oi] = v;
    }
  }
}

// ---------- launch ----------

extern "C" void kernel_launch(void* const* d_in, const int* in_sizes, int n_in,
                              void* d_out, int out_size, void* d_ws, size_t ws_size,
                              hipStream_t stream) {
  const float* x     = (const float*)d_in[0];
  const int*   edge  = (const int*)d_in[1];
  const float* W1    = (const float*)d_in[2];
  const float* b1    = (const float*)d_in[3];
  const float* Wm    = (const float*)d_in[4];
  const float* bm    = (const float*)d_in[5];
  const float* Wv    = (const float*)d_in[6];
  const float* bv    = (const float*)d_in[7];
  const float* noise = (const float*)d_in[8];
  int n = in_sizes[0] / 128;
  int e = in_sizes[1] / 2;
  const int* src = edge;
  const int* dst = edge + e;
  int nc = (n + CMASK) >> CSHIFT;   // 49 coarse buckets of 2048 nodes

  // workspace layout (int units, 16B-aligned segments)
  int* ccnt = (int*)d_ws;                          // NCMAX*16 (1 per 64B line)
  int* ccur = ccnt + NCMAX * 16;                   // NCMAX*16
  int* coff = ccur + NCMAX * 16;                   // NCMAX+1 (+pad)
  int* off  = coff + (NCMAX + 4);                  // n+1 (+pad)
  float* dinv = (float*)(off + ((n + 4) & ~3));    // n
  unsigned int* packed = (unsigned int*)(dinv + ((n + 3) & ~3)); // e
  int* csr  = (int*)(packed + ((e + 3) & ~3));     // e
  unsigned int* h1b = (unsigned int*)(csr + ((e + 3) & ~3)); // n*16 (fp8 h1')
  unsigned int* hb  = h1b + (size_t)n * 16;                  // n*16 (fp8 h')
  unsigned int* aggb = hb + (size_t)n * 16;                  // n*32 (bf16 agg2)

  float* outZ  = (float*)d_out;
  float* outM  = outZ + (size_t)n * 32;
  float* outLv = outM + (size_t)n * 32;

  int ntiles = (e + TILE - 1) / TILE;

  hipMemsetAsync(ccnt, 0, (size_t)NCMAX * 16 * sizeof(int), stream);
  coarse_hist_kernel<<<512, 256, 0, stream>>>(dst, ccnt, e);
  coarse_scan_kernel<<<1, 64, 0, stream>>>(ccnt, coff, ccur, off, nc, n, e);
  coarse_partition_kernel<<<ntiles, 256, 0, stream>>>(src, dst, ccur, packed, e);
  csr_fine_kernel<<<nc, 512, 0, stream>>>(packed, coff, off, dinv, csr, n);
  gemm1_kernel<<<(n + 63) / 64, 256, 0, stream>>>(x, W1, dinv, h1b, n);
  agg_kernel<1><<<(n + 7) / 8, 256, 0, stream>>>((const uint4*)h1b, off, csr, dinv, b1, hb, n);
  agg_kernel<0><<<(n + 7) / 8, 256, 0, stream>>>((const uint4*)hb, off, csr, dinv, b1, aggb, n);
  final_kernel<<<(n + 63) / 64, 256, 0, stream>>>(aggb, Wm, bm, Wv, bv, noise, outZ, outM, outLv, n);
}

// Round 14
// 170.375 us; speedup vs baseline: 1.6901x; 1.0832x over previous
//
#include <hip/hip_runtime.h>
#include <math.h>

#define TILE 4096          // edges per partition tile
#define CSHIFT 10          // coarse bucket = dst >> 10  (1024 nodes)
#define CMASK 1023
#define NCMAX 128

typedef __attribute__((ext_vector_type(8))) short bf16x8;   // 8 bf16 (4 VGPRs)
typedef __attribute__((ext_vector_type(4))) float f32x4;
typedef __attribute__((ext_vector_type(2))) float f32x2;

// ---------- helpers ----------

__device__ __forceinline__ unsigned int pack_bf16(float a, float b) {
  unsigned int ua = __float_as_uint(a);
  ua += 0x7FFFu + ((ua >> 16) & 1u);
  unsigned int ub = __float_as_uint(b);
  ub += 0x7FFFu + ((ub >> 16) & 1u);
  return (ua >> 16) | (ub & 0xFFFF0000u);
}

__device__ __forceinline__ f32x2 shfl_xor2(f32x2 v, int m) {
  f32x2 r;
  r[0] = __shfl_xor(v[0], m);
  r[1] = __shfl_xor(v[1], m);
  return r;
}

// a2[0..7] += fp8x16(hv)  (e4m3 HW decode, packed f32 accumulate)
__device__ __forceinline__ void add16_fp8_pk(f32x2* a2, uint4 hv) {
  unsigned int u[4] = {hv.x, hv.y, hv.z, hv.w};
#pragma unroll
  for (int i = 0; i < 4; ++i) {
    a2[2 * i]     += __builtin_amdgcn_cvt_pk_f32_fp8(u[i], false);
    a2[2 * i + 1] += __builtin_amdgcn_cvt_pk_f32_fp8(u[i], true);
  }
}

__device__ __forceinline__ void fma4(float4& acc, float s, const float4& w) {
  acc.x = fmaf(s, w.x, acc.x);
  acc.y = fmaf(s, w.y, acc.y);
  acc.z = fmaf(s, w.z, acc.z);
  acc.w = fmaf(s, w.w, acc.w);
}

// ---------- CSR build: two-level LDS-staged split ----------

// 4 LDS replicas per bucket to cut same-address atomic serialization
__global__ __launch_bounds__(256) void coarse_hist_kernel(const int* __restrict__ dst,
    int* __restrict__ ccnt, int e) {
  __shared__ int h[NCMAX * 4];
  for (int i = threadIdx.x; i < NCMAX * 4; i += 256) h[i] = 0;
  __syncthreads();
  int rep = threadIdx.x & 3;
  for (int i = blockIdx.x * 256 + threadIdx.x; i < e; i += gridDim.x * 256)
    atomicAdd(&h[((dst[i] >> CSHIFT) << 2) | rep], 1);
  __syncthreads();
  for (int i = threadIdx.x; i < NCMAX; i += 256) {
    int s = h[i * 4] + h[i * 4 + 1] + h[i * 4 + 2] + h[i * 4 + 3];
    if (s) atomicAdd(&ccnt[i * 16], s);
  }
}

// single wave: exclusive scan of NCMAX coarse counts (2 per lane); off[n]=e.
// Buckets >= nc have zero counts (memset), so coff[nc] lands = e naturally.
__global__ __launch_bounds__(64) void coarse_scan_kernel(const int* __restrict__ ccnt,
    int* __restrict__ coff, int* __restrict__ ccur, int* __restrict__ off,
    int nc, int n, int e) {
  int t = threadIdx.x;
  int ia = 2 * t, ib = 2 * t + 1;
  int va = ccnt[ia * 16];
  int vb = ccnt[ib * 16];
  int v = va + vb;
  int incl = v;
#pragma unroll
  for (int ofs = 1; ofs < 64; ofs <<= 1) {
    int w = __shfl_up(incl, ofs);
    if (t >= ofs) incl += w;
  }
  int ex = incl - v;
  coff[ia] = ex;      ccur[ia * 16] = ex;
  coff[ib] = ex + va; ccur[ib * 16] = ex + va;
  if (t == 63) coff[NCMAX] = incl;
  if (t == 0) off[n] = e;
}

// LDS-staged partition: sort a 4096-edge tile by coarse bucket in LDS, reserve
// a global range per bucket with ONE atomic, stream out contiguous segments.
__global__ __launch_bounds__(256) void coarse_partition_kernel(const int* __restrict__ src,
    const int* __restrict__ dst, int* __restrict__ ccur,
    unsigned int* __restrict__ packed, int e) {
  __shared__ unsigned int stage[TILE];
  __shared__ unsigned char bid[TILE];
  __shared__ int hist[NCMAX], excl[NCMAX], gbase[NCMAX], lcur[NCMAX];
  int ntiles = (e + TILE - 1) / TILE;
  for (int tile = blockIdx.x; tile < ntiles; tile += gridDim.x) {
    int i0 = tile * TILE;
    int cnt = e - i0; if (cnt > TILE) cnt = TILE;
    for (int i = threadIdx.x; i < NCMAX; i += 256) hist[i] = 0;
    __syncthreads();
    int myS[16], myD[16];
#pragma unroll
    for (int k = 0; k < 16; ++k) {
      int li = threadIdx.x + k * 256;
      if (li < cnt) {
        myS[k] = src[i0 + li];
        myD[k] = dst[i0 + li];
        atomicAdd(&hist[myD[k] >> CSHIFT], 1);
      }
    }
    __syncthreads();
    if (threadIdx.x < 64) {  // wave 0: scan 128 buckets, 2 per lane
      int t = threadIdx.x;
      int va = hist[2 * t], vb = hist[2 * t + 1];
      int v = va + vb;
      int incl = v;
#pragma unroll
      for (int ofs = 1; ofs < 64; ofs <<= 1) {
        int w = __shfl_up(incl, ofs);
        if (t >= ofs) incl += w;
      }
      int ex = incl - v;
      excl[2 * t] = ex;          lcur[2 * t] = ex;
      excl[2 * t + 1] = ex + va; lcur[2 * t + 1] = ex + va;
    }
    __syncthreads();
#pragma unroll
    for (int k = 0; k < 16; ++k) {
      int li = threadIdx.x + k * 256;
      if (li < cnt) {
        int c = myD[k] >> CSHIFT;
        int p = atomicAdd(&lcur[c], 1);
        stage[p] = (unsigned int)myS[k] | ((unsigned int)(myD[k] & CMASK) << 17);
        bid[p] = (unsigned char)c;
      }
    }
    __syncthreads();
    for (int i = threadIdx.x; i < NCMAX; i += 256) {
      int cc = lcur[i] - excl[i];
      gbase[i] = cc ? atomicAdd(&ccur[i * 16], cc) : 0;
    }
    __syncthreads();
    for (int i = threadIdx.x; i < cnt; i += 256) {
      int c = bid[i];
      packed[gbase[c] + (i - excl[c])] = stage[i];
    }
    __syncthreads();  // protect hist/stage reuse
  }
}

// one block per coarse bucket: counting sort 1024 node sub-buckets -> csr, off, dinv.
__global__ __launch_bounds__(512) void csr_fine_kernel(const unsigned int* __restrict__ packed,
    const int* __restrict__ coff, int* __restrict__ off, float* __restrict__ dinv,
    int* __restrict__ csr, int n) {
  __shared__ int lh[1024];
  __shared__ int lsum[512];
  int b = blockIdx.x;
  int t = threadIdx.x;
  int e0 = coff[b], e1 = coff[b + 1];
  int node0 = b << CSHIFT;
  for (int i = t; i < 1024; i += 512) lh[i] = 0;
  __syncthreads();
  for (int i = e0 + t; i < e1; i += 512) atomicAdd(&lh[packed[i] >> 17], 1);
  __syncthreads();
  int base = t * 2;
  int v0 = lh[base], v1 = lh[base + 1];
  int tsum = v0 + v1;
  lsum[t] = tsum;
  __syncthreads();
  for (int ofs = 1; ofs < 512; ofs <<= 1) {
    int add = (t >= ofs) ? lsum[t - ofs] : 0;
    __syncthreads();
    lsum[t] += add;
    __syncthreads();
  }
  int ex = lsum[t] - tsum;
  lh[base] = ex; lh[base + 1] = ex + v0;
  int node = node0 + base;
  if (node < n)     { off[node]     = e0 + ex;      dinv[node]     = rsqrtf((float)(v0 + 1)); }
  if (node + 1 < n) { off[node + 1] = e0 + ex + v0; dinv[node + 1] = rsqrtf((float)(v1 + 1)); }
  __syncthreads();
  for (int i = e0 + t; i < e1; i += 512) {
    unsigned int p = packed[i];
    int nl = p >> 17;
    int pos = atomicAdd(&lh[nl], 1);
    csr[e0 + pos] = (int)(p & 0x1FFFFu);
  }
}

// ---------- h1' = dinv * (x @ W1) via MFMA, output fp8 e4m3 ----------
__global__ __launch_bounds__(256) void gemm1_kernel(const float* __restrict__ x,
    const float* __restrict__ W1, const float* __restrict__ dinv,
    unsigned int* __restrict__ h1, int n) {
  __shared__ unsigned int xs[64 * 64];  // 16 KB
  __shared__ unsigned int wt[64 * 64];  // 16 KB
  // W1[k][c] -> wt[c][k-pairs], bf16-packed, swizzled
  for (int i = threadIdx.x; i < 4096; i += 256) {
    int c = i & 63, kp = i >> 6;             // kp = k-pair index 0..63
    float a = W1[(2 * kp) * 64 + c];
    float b = W1[(2 * kp + 1) * 64 + c];
    int slot = kp >> 2;                      // 16B slot (4 uints)
    int slotS = slot ^ (c & 7);
    wt[c * 64 + slotS * 4 + (kp & 3)] = pack_bf16(a, b);
  }
  int row0 = blockIdx.x * 64;
  int nrow = n - row0; if (nrow > 64) nrow = 64;
  // x tile -> bf16, swizzled
  for (int i = threadIdx.x; i < 64 * 32; i += 256) {
    int r = i >> 5, q = i & 31;              // q = float4 quad (k = 4q..4q+3)
    float4 v = make_float4(0.f, 0.f, 0.f, 0.f);
    if (r < nrow) v = ((const float4*)(x + (size_t)(row0 + r) * 128))[q];
    int slot = q >> 1;
    int slotS = slot ^ (r & 7);
    int bi = r * 64 + slotS * 4 + (q & 1) * 2;
    xs[bi]     = pack_bf16(v.x, v.y);
    xs[bi + 1] = pack_bf16(v.z, v.w);
  }
  __syncthreads();
  int lane = threadIdx.x & 63;
  int w = threadIdx.x >> 6;
  int rl = lane & 15;
  int g = lane >> 4;
  f32x4 acc[4];
#pragma unroll
  for (int i = 0; i < 4; ++i) acc[i] = (f32x4){0.f, 0.f, 0.f, 0.f};
#pragma unroll
  for (int ks = 0; ks < 4; ++ks) {
    int as = ((ks * 4 + g) ^ (rl & 7)) * 4;
    bf16x8 af = *reinterpret_cast<const bf16x8*>(&xs[(w * 16 + rl) * 64 + as]);
#pragma unroll
    for (int nt = 0; nt < 4; ++nt) {
      int col = nt * 16 + rl;
      int bs = ((ks * 4 + g) ^ (col & 7)) * 4;
      bf16x8 bfr = *reinterpret_cast<const bf16x8*>(&wt[col * 64 + bs]);
      acc[nt] = __builtin_amdgcn_mfma_f32_16x16x32_bf16(af, bfr, acc[nt], 0, 0, 0);
    }
  }
  // epilogue: reg i -> row_local = g*4+i, col = nt*16+rl; scale by dinv, fp8 pairs
#pragma unroll
  for (int i = 0; i < 4; ++i) {
    int row = row0 + w * 16 + g * 4 + i;
    float dv = (row < n) ? dinv[row] : 0.f;
#pragma unroll
    for (int nt = 0; nt < 4; ++nt) {
      float val = dv * acc[nt][i];
      float pv = __shfl_xor(val, 1);
      if (!(lane & 1) && row < n) {
        unsigned int pk = __builtin_amdgcn_cvt_pk_fp8_f32(val, pv, 0u, false);
        ((unsigned short*)h1)[(size_t)row * 32 + nt * 8 + (rl >> 1)] = (unsigned short)pk;
      }
    }
  }
}

// ---------- aggregation ----------
// 2 nodes x 16 edge-slots x 2 feature-lanes per wave. Rows: 64B fp8 e4m3.
// Packed-f32 accumulators (f32x2 -> v_pk_add_f32): decode = 2 cvt + 2 pk_add
// per uint, reduce tree on 16 pairs (15 steps) instead of 32 scalars (30).
// Final pair IS two consecutive features (cvt_pk pairs are consecutive).
// EPI=1: out = fp8( dinv * tanh(result + bias) )  (layer-2 table, 64B rows)
// EPI=0: out = bf16( result )                     (final agg, 128B rows)
template <int EPI>
__global__ __launch_bounds__(256) void agg_kernel(const uint4* __restrict__ h4,
    const int* __restrict__ off, const int* __restrict__ csr,
    const float* __restrict__ dinv, const float* __restrict__ bias,
    unsigned int* __restrict__ out, int n) {
  int lane = threadIdx.x & 63;
  int nd = lane >> 5;            // which of the wave's 2 nodes
  int j  = (lane >> 1) & 15;     // edge slot 0..15
  int fl = lane & 1;             // feature half (32 features per lane)
  int node = blockIdx.x * 8 + (threadIdx.x >> 6) * 2 + nd;
  bool valid = node < n;
  f32x2 acc2[16];
#pragma unroll
  for (int i = 0; i < 16; ++i) acc2[i] = (f32x2){0.f, 0.f};
  if (valid) {
    if (j == 0) {  // self loop
      const uint4* hp = &h4[(size_t)node * 4 + fl * 2];
      uint4 a = hp[0], b = hp[1];
      add16_fp8_pk(acc2, a); add16_fp8_pk(acc2 + 8, b);
    }
    int e1 = off[node + 1];
    for (int ee = off[node] + j; ee < e1; ee += 16) {
      int s = __builtin_nontemporal_load(&csr[ee]);
      const uint4* hp = &h4[(size_t)s * 4 + fl * 2];
      uint4 a = hp[0], b = hp[1];
      add16_fp8_pk(acc2, a); add16_fp8_pk(acc2 + 8, b);
    }
  }
  // reduce over slot bits (lane bits 1..4); 16 pairs -> 1 pair per lane
#pragma unroll
  for (int i = 0; i < 8; ++i) {
    f32x2 tlo = acc2[i]     + shfl_xor2(acc2[i], 2);
    f32x2 thi = acc2[i + 8] + shfl_xor2(acc2[i + 8], 2);
    acc2[i] = (j & 1) ? thi : tlo;
  }
#pragma unroll
  for (int i = 0; i < 4; ++i) {
    f32x2 tlo = acc2[i]     + shfl_xor2(acc2[i], 4);
    f32x2 thi = acc2[i + 4] + shfl_xor2(acc2[i + 4], 4);
    acc2[i] = (j & 2) ? thi : tlo;
  }
#pragma unroll
  for (int i = 0; i < 2; ++i) {
    f32x2 tlo = acc2[i]     + shfl_xor2(acc2[i], 8);
    f32x2 thi = acc2[i + 2] + shfl_xor2(acc2[i + 2], 8);
    acc2[i] = (j & 4) ? thi : tlo;
  }
  {
    f32x2 tlo = acc2[0] + shfl_xor2(acc2[0], 16);
    f32x2 thi = acc2[1] + shfl_xor2(acc2[1], 16);
    acc2[0] = (j & 8) ? thi : tlo;
  }
  // lane owns feature pair q: bit i of j selected pair-bit (3-i)
  int q = 8 * (j & 1) + 4 * ((j >> 1) & 1) + 2 * ((j >> 2) & 1) + ((j >> 3) & 1);
  int f0 = fl * 32 + 2 * q;
  if (valid) {
    float di = dinv[node];
    if (EPI) {
      float v0 = di * tanhf(fmaf(di, acc2[0][0], bias[f0]));
      float v1 = di * tanhf(fmaf(di, acc2[0][1], bias[f0 + 1]));
      unsigned int pk = __builtin_amdgcn_cvt_pk_fp8_f32(v0, v1, 0u, false);
      ((unsigned short*)out)[(size_t)node * 32 + fl * 16 + q] = (unsigned short)pk;
    } else {
      float v0 = di * acc2[0][0];
      float v1 = di * acc2[0][1];
      out[(size_t)node * 32 + fl * 16 + q] = pack_bf16(v0, v1);
    }
  }
}

// ---------- final: mean/logvar GEMMs + reparam ----------
__global__ __launch_bounds__(256) void final_kernel(const unsigned int* __restrict__ aggb,
    const float* __restrict__ Wm, const float* __restrict__ bm,
    const float* __restrict__ Wv, const float* __restrict__ bv,
    const float* __restrict__ noise, float* __restrict__ outZ,
    float* __restrict__ outM, float* __restrict__ outLv, int n) {
  __shared__ float WmS[64 * 32];
  __shared__ float WvS[64 * 32];
  __shared__ float aggS[64 * 68];  // stride 68 breaks bank conflicts
  for (int i = threadIdx.x; i < 64 * 8; i += 256) {
    ((float4*)WmS)[i] = ((const float4*)Wm)[i];
    ((float4*)WvS)[i] = ((const float4*)Wv)[i];
  }
  int row0 = blockIdx.x * 64;
  int nrow = n - row0; if (nrow > 64) nrow = 64;
  for (int i = threadIdx.x; i < 64 * 16; i += 256) {
    int r = i >> 4, g = i & 15;
    uint2 u = make_uint2(0u, 0u);
    if (r < nrow) u = ((const uint2*)aggb)[(size_t)(row0 + r) * 16 + g];
    float* d = &aggS[r * 68 + g * 4];
    d[0] = __uint_as_float(u.x << 16);
    d[1] = __uint_as_float(u.x & 0xFFFF0000u);
    d[2] = __uint_as_float(u.y << 16);
    d[3] = __uint_as_float(u.y & 0xFFFF0000u);
  }
  __syncthreads();
  int c4 = (threadIdx.x & 7) * 4;
  int r2 = (threadIdx.x >> 3) * 2;
  float4 am[2], av[2];
#pragma unroll
  for (int i = 0; i < 2; ++i) {
    am[i] = make_float4(0.f, 0.f, 0.f, 0.f);
    av[i] = make_float4(0.f, 0.f, 0.f, 0.f);
  }
#pragma unroll 4
  for (int kq = 0; kq < 16; ++kq) {
    float4 xa[2], wm[4], wv[4];
#pragma unroll
    for (int i = 0; i < 2; ++i) xa[i] = *(const float4*)&aggS[(r2 + i) * 68 + kq * 4];
#pragma unroll
    for (int q = 0; q < 4; ++q) {
      wm[q] = *(const float4*)&WmS[(kq * 4 + q) * 32 + c4];
      wv[q] = *(const float4*)&WvS[(kq * 4 + q) * 32 + c4];
    }
#pragma unroll
    for (int i = 0; i < 2; ++i) {
      fma4(am[i], xa[i].x, wm[0]); fma4(am[i], xa[i].y, wm[1]);
      fma4(am[i], xa[i].z, wm[2]); fma4(am[i], xa[i].w, wm[3]);
      fma4(av[i], xa[i].x, wv[0]); fma4(av[i], xa[i].y, wv[1]);
      fma4(av[i], xa[i].z, wv[2]); fma4(av[i], xa[i].w, wv[3]);
    }
  }
  float4 bmv = *(const float4*)&bm[c4];
  float4 bvv = *(const float4*)&bv[c4];
#pragma unroll
  for (int i = 0; i < 2; ++i) {
    int row = row0 + r2 + i;
    if (row < n) {
      float4 m = am[i]; m.x += bmv.x; m.y += bmv.y; m.z += bmv.z; m.w += bmv.w;
      float4 v = av[i]; v.x += bvv.x; v.y += bvv.y; v.z += bvv.z; v.w += bvv.w;
      size_t oi = (size_t)row * 8 + (threadIdx.x & 7);
      float4 nz = ((const float4*)noise)[oi];
      float4 z;
      z.x = fmaf(nz.x, expf(0.5f * v.x), m.x);
      z.y = fmaf(nz.y, expf(0.5f * v.y), m.y);
      z.z = fmaf(nz.z, expf(0.5f * v.z), m.z);
      z.w = fmaf(nz.w, expf(0.5f * v.w), m.w);
      ((float4*)outZ)[oi] = z;
      ((float4*)outM)[oi] = m;
      ((float4*)outLv)[oi] = v;
    }
  }
}

// ---------- launch ----------

extern "C" void kernel_launch(void* const* d_in, const int* in_sizes, int n_in,
                              void* d_out, int out_size, void* d_ws, size_t ws_size,
                              hipStream_t stream) {
  const float* x     = (const float*)d_in[0];
  const int*   edge  = (const int*)d_in[1];
  const float* W1    = (const float*)d_in[2];
  const float* b1    = (const float*)d_in[3];
  const float* Wm    = (const float*)d_in[4];
  const float* bm    = (const float*)d_in[5];
  const float* Wv    = (const float*)d_in[6];
  const float* bv    = (const float*)d_in[7];
  const float* noise = (const float*)d_in[8];
  int n = in_sizes[0] / 128;
  int e = in_sizes[1] / 2;
  const int* src = edge;
  const int* dst = edge + e;
  int nc = (n + CMASK) >> CSHIFT;   // 98 coarse buckets of 1024 nodes

  // workspace layout (int units, 16B-aligned segments)
  int* ccnt = (int*)d_ws;                          // NCMAX*16 (1 per 64B line)
  int* ccur = ccnt + NCMAX * 16;                   // NCMAX*16
  int* coff = ccur + NCMAX * 16;                   // NCMAX+1 (+pad)
  int* off  = coff + (NCMAX + 4);                  // n+1 (+pad)
  float* dinv = (float*)(off + ((n + 4) & ~3));    // n
  unsigned int* packed = (unsigned int*)(dinv + ((n + 3) & ~3)); // e
  int* csr  = (int*)(packed + ((e + 3) & ~3));     // e
  unsigned int* h1b = (unsigned int*)(csr + ((e + 3) & ~3)); // n*16 (fp8 h1')
  unsigned int* hb  = h1b + (size_t)n * 16;                  // n*16 (fp8 h')
  unsigned int* aggb = hb + (size_t)n * 16;                  // n*32 (bf16 agg2)

  float* outZ  = (float*)d_out;
  float* outM  = outZ + (size_t)n * 32;
  float* outLv = outM + (size_t)n * 32;

  int ntiles = (e + TILE - 1) / TILE;

  hipMemsetAsync(ccnt, 0, (size_t)NCMAX * 16 * sizeof(int), stream);
  coarse_hist_kernel<<<512, 256, 0, stream>>>(dst, ccnt, e);
  coarse_scan_kernel<<<1, 64, 0, stream>>>(ccnt, coff, ccur, off, nc, n, e);
  coarse_partition_kernel<<<ntiles, 256, 0, stream>>>(src, dst, ccur, packed, e);
  csr_fine_kernel<<<nc, 512, 0, stream>>>(packed, coff, off, dinv, csr, n);
  gemm1_kernel<<<(n + 63) / 64, 256, 0, stream>>>(x, W1, dinv, h1b, n);
  agg_kernel<1><<<(n + 7) / 8, 256, 0, stream>>>((const uint4*)h1b, off, csr, dinv, b1, hb, n);
  agg_kernel<0><<<(n + 7) / 8, 256, 0, stream>>>((const uint4*)hb, off, csr, dinv, b1, aggb, n);
  final_kernel<<<(n + 63) / 64, 256, 0, stream>>>(aggb, Wm, bm, Wv, bv, noise, outZ, outM, outLv, n);
}